// Round 1
// baseline (654.690 us; speedup 1.0000x reference)
//
#include <hip/hip_runtime.h>

typedef __attribute__((ext_vector_type(8))) __bf16 bf16x8;
typedef __attribute__((ext_vector_type(4))) float f32x4;

__device__ __forceinline__ ushort f2b(float f) {
    uint u = __builtin_bit_cast(uint, f);
    u += 0x7fffu + ((u >> 16) & 1u);
    return (ushort)(u >> 16);
}
__device__ __forceinline__ float b2f(ushort h) {
    uint u = ((uint)h) << 16;
    return __builtin_bit_cast(float, u);
}

// ---------------- cast f32 -> bf16 (vec4) ----------------
__global__ __launch_bounds__(256) void cast_kernel(const float* __restrict__ src,
                                                   ushort* __restrict__ dst) {
    size_t i = ((size_t)blockIdx.x * 256 + threadIdx.x) * 4;
    float4 v = *(const float4*)(src + i);
    ushort4 o;
    o.x = f2b(v.x); o.y = f2b(v.y); o.z = f2b(v.z); o.w = f2b(v.w);
    *(ushort4*)(dst + i) = o;
}

// ---------------- LayerNorm(query) -> bf16 into xq[:,1024:2048] ----------------
__global__ __launch_bounds__(256) void ln_kernel(const float* __restrict__ x,
                                                 const float* __restrict__ ga,
                                                 const float* __restrict__ be,
                                                 ushort* __restrict__ xq) {
    const int row = blockIdx.x, tid = threadIdx.x;
    __shared__ float red[4];
    float4 v = ((const float4*)(x + (size_t)row * 1024))[tid];
    float sm = v.x + v.y + v.z + v.w;
    for (int off = 32; off; off >>= 1) sm += __shfl_xor(sm, off);
    if ((tid & 63) == 0) red[tid >> 6] = sm;
    __syncthreads();
    float mean = (red[0] + red[1] + red[2] + red[3]) * (1.f / 1024.f);
    __syncthreads();
    float dx = v.x - mean, dy = v.y - mean, dz = v.z - mean, dw = v.w - mean;
    float s2 = dx * dx + dy * dy + dz * dz + dw * dw;
    for (int off = 32; off; off >>= 1) s2 += __shfl_xor(s2, off);
    if ((tid & 63) == 0) red[tid >> 6] = s2;
    __syncthreads();
    float var = (red[0] + red[1] + red[2] + red[3]) * (1.f / 1023.f);
    float inv = 1.f / (sqrtf(var) + 1e-6f);
    float4 g = ((const float4*)ga)[tid];
    float4 bb = ((const float4*)be)[tid];
    ushort4 o;
    o.x = f2b(g.x * dx * inv + bb.x);
    o.y = f2b(g.y * dy * inv + bb.y);
    o.z = f2b(g.z * dz * inv + bb.z);
    o.w = f2b(g.w * dw * inv + bb.w);
    *(ushort4*)&xq[(size_t)row * 2048 + 1024 + tid * 4] = o;
}

// ---------------- GEMM: C[m][n] = (sum_k A[m][k]*B[n][k] + bias[n]) * scale ----------------
// A: (M x K) bf16 row-major, lda. B: (N x K) bf16 row-major, ldb.
// mode 0: C bf16 row-major (ldc). mode 1: V-transposed store to Vt (B,H,128,S=1024).
__global__ __launch_bounds__(256) void gemm_bt(const ushort* __restrict__ A, int lda,
                                               const ushort* __restrict__ B, int ldb,
                                               const float* __restrict__ bias,
                                               ushort* __restrict__ C, int ldc,
                                               int K, float scale, int mode) {
    __shared__ ushort As[128 * 32];
    __shared__ ushort Bs[128 * 32];
    const int tid = threadIdx.x;
    const int w = tid >> 6, l = tid & 63;
    const int wr = w >> 1, wc = w & 1;
    const int m0 = blockIdx.x * 128, n0 = blockIdx.y * 128;
    const int lrow = l >> 2, lcol = (l & 3) * 8;
    const int r16 = l & 15, g4 = l >> 4;

    f32x4 acc[4][4];
#pragma unroll
    for (int i = 0; i < 4; i++)
#pragma unroll
        for (int j = 0; j < 4; j++) acc[i][j] = (f32x4){0.f, 0.f, 0.f, 0.f};

    const ushort* Ag0 = A + (size_t)(m0 + w * 16 + lrow) * lda + lcol;
    const ushort* Bg0 = B + (size_t)(n0 + w * 16 + lrow) * ldb + lcol;
    ushort* lA = As + w * 512;
    ushort* lB = Bs + w * 512;

    for (int k0 = 0; k0 < K; k0 += 32) {
        __builtin_amdgcn_global_load_lds((const __attribute__((address_space(1))) void*)(Ag0 + k0),
                                         (__attribute__((address_space(3))) void*)(lA), 16, 0, 0);
        __builtin_amdgcn_global_load_lds((const __attribute__((address_space(1))) void*)(Ag0 + (size_t)64 * lda + k0),
                                         (__attribute__((address_space(3))) void*)(lA + 2048), 16, 0, 0);
        __builtin_amdgcn_global_load_lds((const __attribute__((address_space(1))) void*)(Bg0 + k0),
                                         (__attribute__((address_space(3))) void*)(lB), 16, 0, 0);
        __builtin_amdgcn_global_load_lds((const __attribute__((address_space(1))) void*)(Bg0 + (size_t)64 * ldb + k0),
                                         (__attribute__((address_space(3))) void*)(lB + 2048), 16, 0, 0);
        __syncthreads();
        bf16x8 af[4], bfr[4];
#pragma unroll
        for (int mi = 0; mi < 4; mi++)
            af[mi] = *(const bf16x8*)&As[(wr * 64 + mi * 16 + r16) * 32 + g4 * 8];
#pragma unroll
        for (int ni = 0; ni < 4; ni++)
            bfr[ni] = *(const bf16x8*)&Bs[(wc * 64 + ni * 16 + r16) * 32 + g4 * 8];
#pragma unroll
        for (int mi = 0; mi < 4; mi++)
#pragma unroll
            for (int ni = 0; ni < 4; ni++)
                acc[mi][ni] = __builtin_amdgcn_mfma_f32_16x16x32_bf16(af[mi], bfr[ni], acc[mi][ni], 0, 0, 0);
        __syncthreads();
    }

    const int row0 = m0 + wr * 64;
    const int col0 = n0 + wc * 64;
    if (mode == 0) {
#pragma unroll
        for (int ni = 0; ni < 4; ni++) {
            int n = col0 + ni * 16 + r16;
            float bs = bias[n];
#pragma unroll
            for (int mi = 0; mi < 4; mi++) {
                int mr = row0 + mi * 16 + g4 * 4;
#pragma unroll
                for (int r = 0; r < 4; r++) {
                    C[(size_t)(mr + r) * ldc + n] = f2b((acc[mi][ni][r] + bs) * scale);
                }
            }
        }
    } else {
        // Vt[(b*8+h)*128 + d][s], m = b*1024+s, n = h*128+d
#pragma unroll
        for (int ni = 0; ni < 4; ni++) {
            int n = col0 + ni * 16 + r16;
            float bs = bias[n];
            int h = n >> 7, d = n & 127;
#pragma unroll
            for (int mi = 0; mi < 4; mi++) {
                int m = row0 + mi * 16 + g4 * 4;
                int b_ = m >> 10, s_ = m & 1023;
                ushort4 o;
                o.x = f2b((acc[mi][ni][0] + bs) * scale);
                o.y = f2b((acc[mi][ni][1] + bs) * scale);
                o.z = f2b((acc[mi][ni][2] + bs) * scale);
                o.w = f2b((acc[mi][ni][3] + bs) * scale);
                *(ushort4*)&C[((size_t)(b_ * 8 + h) * 128 + d) * 1024 + s_] = o;
            }
        }
    }
}

// ---------------- flash attention: per block (b,h,64 q-rows), 4 waves x 16 rows ----------------
__global__ __launch_bounds__(256) void attn_kernel(const ushort* __restrict__ Q,
                                                   const ushort* __restrict__ Kt,
                                                   const ushort* __restrict__ Vt,
                                                   const int* __restrict__ mask,
                                                   ushort* __restrict__ xq) {
    __shared__ ushort Pl[4][16 * 64];
    const int l = threadIdx.x & 63, wid = threadIdx.x >> 6;
    const int bh = blockIdx.y;
    const int b = bh >> 3, h = bh & 7;
    const int q0 = blockIdx.x * 64 + wid * 16;
    const int r16 = l & 15, g4 = l >> 4;

    bf16x8 qf[4];
    const ushort* Qrow = Q + (size_t)(b * 1024 + q0 + r16) * 1024 + h * 128 + g4 * 8;
#pragma unroll
    for (int kf = 0; kf < 4; kf++) qf[kf] = *(const bf16x8*)(Qrow + kf * 32);

    f32x4 xacc[8];
#pragma unroll
    for (int i = 0; i < 8; i++) xacc[i] = (f32x4){0.f, 0.f, 0.f, 0.f};
    float mrow[4], lrow[4];
#pragma unroll
    for (int r = 0; r < 4; r++) { mrow[r] = -INFINITY; lrow[r] = 0.f; }

    const ushort* Kbase = Kt + (size_t)(b * 1024) * 1024 + h * 128 + g4 * 8;
    const ushort* Vbase = Vt + ((size_t)(b * 8 + h) * 128) * 1024 + g4 * 8;
    const int* mptr = mask + b * 1024;

    for (int kv0 = 0; kv0 < 1024; kv0 += 64) {
        f32x4 s[4];
#pragma unroll
        for (int cg = 0; cg < 4; cg++) {
            s[cg] = (f32x4){0.f, 0.f, 0.f, 0.f};
            const ushort* kp = Kbase + (size_t)(kv0 + cg * 16 + r16) * 1024;
#pragma unroll
            for (int kf = 0; kf < 4; kf++) {
                bf16x8 kfr = *(const bf16x8*)(kp + kf * 32);
                s[cg] = __builtin_amdgcn_mfma_f32_16x16x32_bf16(qf[kf], kfr, s[cg], 0, 0, 0);
            }
            int mk = mptr[kv0 + cg * 16 + r16];
            if (mk == 0) { s[cg][0] = -1e9f; s[cg][1] = -1e9f; s[cg][2] = -1e9f; s[cg][3] = -1e9f; }
        }
        // online softmax per row (rows spread: row = g4*4 + r, cols = lane&15 within cg)
        float scl[4];
#pragma unroll
        for (int r = 0; r < 4; r++) {
            float v = fmaxf(fmaxf(s[0][r], s[1][r]), fmaxf(s[2][r], s[3][r]));
            v = fmaxf(v, __shfl_xor(v, 1));
            v = fmaxf(v, __shfl_xor(v, 2));
            v = fmaxf(v, __shfl_xor(v, 4));
            v = fmaxf(v, __shfl_xor(v, 8));
            float mn = fmaxf(mrow[r], v);
            scl[r] = __expf(mrow[r] - mn);
            mrow[r] = mn;
        }
        float rsum[4] = {0.f, 0.f, 0.f, 0.f};
#pragma unroll
        for (int cg = 0; cg < 4; cg++) {
#pragma unroll
            for (int r = 0; r < 4; r++) {
                float p = __expf(s[cg][r] - mrow[r]);
                rsum[r] += p;
                Pl[wid][(g4 * 4 + r) * 64 + cg * 16 + r16] = f2b(p);
            }
        }
#pragma unroll
        for (int r = 0; r < 4; r++) {
            float t = rsum[r];
            t += __shfl_xor(t, 1);
            t += __shfl_xor(t, 2);
            t += __shfl_xor(t, 4);
            t += __shfl_xor(t, 8);
            lrow[r] = lrow[r] * scl[r] + t;
        }
#pragma unroll
        for (int cg2 = 0; cg2 < 8; cg2++)
#pragma unroll
            for (int r = 0; r < 4; r++) xacc[cg2][r] *= scl[r];
        asm volatile("s_waitcnt lgkmcnt(0)" ::: "memory");
        __builtin_amdgcn_sched_barrier(0);
#pragma unroll
        for (int ks = 0; ks < 2; ks++) {
            bf16x8 pfr = *(const bf16x8*)&Pl[wid][r16 * 64 + ks * 32 + g4 * 8];
#pragma unroll
            for (int cg2 = 0; cg2 < 8; cg2++) {
                bf16x8 vfr = *(const bf16x8*)(Vbase + (size_t)(cg2 * 16 + r16) * 1024 + kv0 + ks * 32);
                xacc[cg2] = __builtin_amdgcn_mfma_f32_16x16x32_bf16(pfr, vfr, xacc[cg2], 0, 0, 0);
            }
        }
    }
    // write x into xq[:, 0:1024]
#pragma unroll
    for (int cg2 = 0; cg2 < 8; cg2++) {
#pragma unroll
        for (int r = 0; r < 4; r++) {
            float v = xacc[cg2][r] / lrow[r];
            xq[(size_t)(b * 1024 + q0 + g4 * 4 + r) * 2048 + h * 128 + cg2 * 16 + r16] = f2b(v);
        }
    }
}

// ---------------- GLU: out = a * sigmoid(g) ----------------
__global__ __launch_bounds__(256) void glu_kernel(const ushort* __restrict__ z,
                                                  float* __restrict__ out) {
    size_t i = (size_t)blockIdx.x * 1024 + (size_t)threadIdx.x * 4;
    size_t row = i >> 10;
    int c = (int)(i & 1023);
    ushort4 av = *(const ushort4*)&z[row * 2048 + c];
    ushort4 gv = *(const ushort4*)&z[row * 2048 + 1024 + c];
    float4 o;
    o.x = b2f(av.x) * (1.f / (1.f + __expf(-b2f(gv.x))));
    o.y = b2f(av.y) * (1.f / (1.f + __expf(-b2f(gv.y))));
    o.z = b2f(av.z) * (1.f / (1.f + __expf(-b2f(gv.z))));
    o.w = b2f(av.w) * (1.f / (1.f + __expf(-b2f(gv.w))));
    *(float4*)&out[i] = o;
}

extern "C" void kernel_launch(void* const* d_in, const int* in_sizes, int n_in,
                              void* d_out, int out_size, void* d_ws, size_t ws_size,
                              hipStream_t stream) {
    const float* query = (const float*)d_in[0];
    const float* value = (const float*)d_in[1];
    const float* key   = (const float*)d_in[2];
    const int*   mask  = (const int*)d_in[3];
    const float* ln_a  = (const float*)d_in[4];
    const float* ln_b  = (const float*)d_in[5];
    const float* wq    = (const float*)d_in[6];
    const float* bq    = (const float*)d_in[7];
    const float* wk    = (const float*)d_in[8];
    const float* bk    = (const float*)d_in[9];
    const float* wv    = (const float*)d_in[10];
    const float* bv    = (const float*)d_in[11];
    const float* waoa  = (const float*)d_in[12];
    const float* baoa  = (const float*)d_in[13];
    float* out = (float*)d_out;

    char* w8 = (char*)d_ws;
    ushort* xq   = (ushort*)(w8);                 // 8192x2048 bf16 = 33554432 B ([x | q_ln])
    ushort* Qb   = (ushort*)(w8 + 33554432);      // 8192x1024 bf16
    ushort* Kb   = (ushort*)(w8 + 50331648);      // 8192x1024 bf16
    ushort* Vt   = (ushort*)(w8 + 67108864);      // (B,H,128,S) bf16
    ushort* keyb = (ushort*)(w8 + 83886080);      // 8192x1024 bf16
    ushort* valb = (ushort*)(w8 + 100663296);     // 8192x1024 bf16
    ushort* zb   = (ushort*)(w8 + 83886080);      // aliases keyb/valb (dead by AOA time)
    ushort* wqb  = (ushort*)(w8 + 117440512);     // 1024x1024 bf16
    ushort* wkb  = (ushort*)(w8 + 119537664);
    ushort* wvb  = (ushort*)(w8 + 121634816);
    ushort* wab  = (ushort*)(w8 + 123731968);     // 2048x2048 bf16 (ends at 132120576)

    cast_kernel<<<8192, 256, 0, stream>>>(key, keyb);
    cast_kernel<<<8192, 256, 0, stream>>>(value, valb);
    cast_kernel<<<1024, 256, 0, stream>>>(wq, wqb);
    cast_kernel<<<1024, 256, 0, stream>>>(wk, wkb);
    cast_kernel<<<1024, 256, 0, stream>>>(wv, wvb);
    cast_kernel<<<4096, 256, 0, stream>>>(waoa, wab);
    ln_kernel<<<8192, 256, 0, stream>>>(query, ln_a, ln_b, xq);

    const float qscale = 0.08838834764831845f; // 1/sqrt(128)
    gemm_bt<<<dim3(64, 8), 256, 0, stream>>>(xq + 1024, 2048, wqb, 1024, bq, Qb, 1024, 1024, qscale, 0);
    gemm_bt<<<dim3(64, 8), 256, 0, stream>>>(keyb, 1024, wkb, 1024, bk, Kb, 1024, 1024, 1.f, 0);
    gemm_bt<<<dim3(64, 8), 256, 0, stream>>>(valb, 1024, wvb, 1024, bv, Vt, 0, 1024, 1.f, 1);

    attn_kernel<<<dim3(16, 64), 256, 0, stream>>>(Qb, Kb, Vt, mask, xq);

    gemm_bt<<<dim3(64, 16), 256, 0, stream>>>(xq, 2048, wab, 2048, baoa, zb, 2048, 2048, 1.f, 0);
    glu_kernel<<<8192, 256, 0, stream>>>(zb, out);
}

// Round 2
// 327.507 us; speedup vs baseline: 1.9990x; 1.9990x over previous
//
#include <hip/hip_runtime.h>

typedef __attribute__((ext_vector_type(8))) __bf16 bf16x8;
typedef __attribute__((ext_vector_type(4))) float f32x4;

__device__ __forceinline__ ushort f2b(float f) {
    uint u = __builtin_bit_cast(uint, f);
    u += 0x7fffu + ((u >> 16) & 1u);
    return (ushort)(u >> 16);
}
__device__ __forceinline__ float b2f(ushort h) {
    uint u = ((uint)h) << 16;
    return __builtin_bit_cast(float, u);
}

// ---------------- cast f32 -> bf16 (vec4) ----------------
__global__ __launch_bounds__(256) void cast_kernel(const float* __restrict__ src,
                                                   ushort* __restrict__ dst) {
    size_t i = ((size_t)blockIdx.x * 256 + threadIdx.x) * 4;
    float4 v = *(const float4*)(src + i);
    ushort4 o;
    o.x = f2b(v.x); o.y = f2b(v.y); o.z = f2b(v.z); o.w = f2b(v.w);
    *(ushort4*)(dst + i) = o;
}

// ---------------- LayerNorm(query) -> bf16 into xq[:,1024:2048] ----------------
__global__ __launch_bounds__(256) void ln_kernel(const float* __restrict__ x,
                                                 const float* __restrict__ ga,
                                                 const float* __restrict__ be,
                                                 ushort* __restrict__ xq) {
    const int row = blockIdx.x, tid = threadIdx.x;
    __shared__ float red[4];
    float4 v = ((const float4*)(x + (size_t)row * 1024))[tid];
    float sm = v.x + v.y + v.z + v.w;
    for (int off = 32; off; off >>= 1) sm += __shfl_xor(sm, off);
    if ((tid & 63) == 0) red[tid >> 6] = sm;
    __syncthreads();
    float mean = (red[0] + red[1] + red[2] + red[3]) * (1.f / 1024.f);
    __syncthreads();
    float dx = v.x - mean, dy = v.y - mean, dz = v.z - mean, dw = v.w - mean;
    float s2 = dx * dx + dy * dy + dz * dz + dw * dw;
    for (int off = 32; off; off >>= 1) s2 += __shfl_xor(s2, off);
    if ((tid & 63) == 0) red[tid >> 6] = s2;
    __syncthreads();
    float var = (red[0] + red[1] + red[2] + red[3]) * (1.f / 1023.f);
    float inv = 1.f / (sqrtf(var) + 1e-6f);
    float4 g = ((const float4*)ga)[tid];
    float4 bb = ((const float4*)be)[tid];
    ushort4 o;
    o.x = f2b(g.x * dx * inv + bb.x);
    o.y = f2b(g.y * dy * inv + bb.y);
    o.z = f2b(g.z * dz * inv + bb.z);
    o.w = f2b(g.w * dw * inv + bb.w);
    *(ushort4*)&xq[(size_t)row * 2048 + 1024 + tid * 4] = o;
}

// ---------------- GEMM: C[m][n] = (sum_k A[m][k]*B[n][k] + bias[n]) * scale ----------------
__global__ __launch_bounds__(256) void gemm_bt(const ushort* __restrict__ A, int lda,
                                               const ushort* __restrict__ B, int ldb,
                                               const float* __restrict__ bias,
                                               ushort* __restrict__ C, int ldc,
                                               int K, float scale, int mode) {
    __shared__ ushort As[128 * 32];
    __shared__ ushort Bs[128 * 32];
    const int tid = threadIdx.x;
    const int w = tid >> 6, l = tid & 63;
    const int wr = w >> 1, wc = w & 1;
    const int m0 = blockIdx.x * 128, n0 = blockIdx.y * 128;
    const int lrow = l >> 2, lcol = (l & 3) * 8;
    const int r16 = l & 15, g4 = l >> 4;

    f32x4 acc[4][4];
#pragma unroll
    for (int i = 0; i < 4; i++)
#pragma unroll
        for (int j = 0; j < 4; j++) acc[i][j] = (f32x4){0.f, 0.f, 0.f, 0.f};

    const ushort* Ag0 = A + (size_t)(m0 + w * 16 + lrow) * lda + lcol;
    const ushort* Bg0 = B + (size_t)(n0 + w * 16 + lrow) * ldb + lcol;
    ushort* lA = As + w * 512;
    ushort* lB = Bs + w * 512;

    for (int k0 = 0; k0 < K; k0 += 32) {
        __builtin_amdgcn_global_load_lds((const __attribute__((address_space(1))) void*)(Ag0 + k0),
                                         (__attribute__((address_space(3))) void*)(lA), 16, 0, 0);
        __builtin_amdgcn_global_load_lds((const __attribute__((address_space(1))) void*)(Ag0 + (size_t)64 * lda + k0),
                                         (__attribute__((address_space(3))) void*)(lA + 2048), 16, 0, 0);
        __builtin_amdgcn_global_load_lds((const __attribute__((address_space(1))) void*)(Bg0 + k0),
                                         (__attribute__((address_space(3))) void*)(lB), 16, 0, 0);
        __builtin_amdgcn_global_load_lds((const __attribute__((address_space(1))) void*)(Bg0 + (size_t)64 * ldb + k0),
                                         (__attribute__((address_space(3))) void*)(lB + 2048), 16, 0, 0);
        __syncthreads();
        bf16x8 af[4], bfr[4];
#pragma unroll
        for (int mi = 0; mi < 4; mi++)
            af[mi] = *(const bf16x8*)&As[(wr * 64 + mi * 16 + r16) * 32 + g4 * 8];
#pragma unroll
        for (int ni = 0; ni < 4; ni++)
            bfr[ni] = *(const bf16x8*)&Bs[(wc * 64 + ni * 16 + r16) * 32 + g4 * 8];
#pragma unroll
        for (int mi = 0; mi < 4; mi++)
#pragma unroll
            for (int ni = 0; ni < 4; ni++)
                acc[mi][ni] = __builtin_amdgcn_mfma_f32_16x16x32_bf16(af[mi], bfr[ni], acc[mi][ni], 0, 0, 0);
        __syncthreads();
    }

    const int row0 = m0 + wr * 64;
    const int col0 = n0 + wc * 64;
    if (mode == 0) {
#pragma unroll
        for (int ni = 0; ni < 4; ni++) {
            int n = col0 + ni * 16 + r16;
            float bs = bias[n];
#pragma unroll
            for (int mi = 0; mi < 4; mi++) {
                int mr = row0 + mi * 16 + g4 * 4;
#pragma unroll
                for (int r = 0; r < 4; r++) {
                    C[(size_t)(mr + r) * ldc + n] = f2b((acc[mi][ni][r] + bs) * scale);
                }
            }
        }
    } else {
        // Vt[(b*8+h)*128 + d][s], m = b*1024+s, n = h*128+d
#pragma unroll
        for (int ni = 0; ni < 4; ni++) {
            int n = col0 + ni * 16 + r16;
            float bs = bias[n];
            int h = n >> 7, d = n & 127;
#pragma unroll
            for (int mi = 0; mi < 4; mi++) {
                int m = row0 + mi * 16 + g4 * 4;
                int b_ = m >> 10, s_ = m & 1023;
                ushort4 o;
                o.x = f2b((acc[mi][ni][0] + bs) * scale);
                o.y = f2b((acc[mi][ni][1] + bs) * scale);
                o.z = f2b((acc[mi][ni][2] + bs) * scale);
                o.w = f2b((acc[mi][ni][3] + bs) * scale);
                *(ushort4*)&C[((size_t)(b_ * 8 + h) * 128 + d) * 1024 + s_] = o;
            }
        }
    }
}

// ---------------- flash attention v2 ----------------
// Block = (b,h) x 128 q-rows, 8 waves x 16 rows each. K/V tiles (KVBLK=64)
// double-buffered in LDS via global_load_lds (pre-swizzled global source =
// inverse of the XOR read swizzle). Mask preloaded as a 64-bit per-lane bitmask.
__global__ __launch_bounds__(512, 4) void attn_kernel(const ushort* __restrict__ Q,
                                                      const ushort* __restrict__ Kt,
                                                      const ushort* __restrict__ Vt,
                                                      const int* __restrict__ mask,
                                                      ushort* __restrict__ xq) {
    __shared__ ushort Ks[2][8192];   // [64 kv][128 d], row=256B, XOR swz ((row&7)<<4 bytes)
    __shared__ ushort Vs[2][8192];   // [128 d][64 s],  row=128B, XOR swz ((d&7)<<4 bytes)
    __shared__ ushort Pl[8][1024];   // per-wave [16 q][64 kv], XOR swz ((row&7)<<3 elems)

    const int tid = threadIdx.x;
    const int l = tid & 63, wid = tid >> 6;
    const int r16 = l & 15, g4 = l >> 4;
    const int bh = blockIdx.y;
    const int b = bh >> 3, h = bh & 7;
    const int q0 = blockIdx.x * 128 + wid * 16;

    // Q fragments (A operand): lane holds Q[q0+r16][g4*8 + kf*32 ..]
    bf16x8 qf[4];
    const ushort* Qrow = Q + (size_t)(b * 1024 + q0 + r16) * 1024 + h * 128 + g4 * 8;
#pragma unroll
    for (int kf = 0; kf < 4; kf++) qf[kf] = *(const bf16x8*)(Qrow + kf * 32);

    const ushort* Kg = Kt + ((size_t)b * 1024) * 1024 + h * 128; // + s*1024 + d
    const ushort* Vg = Vt + (size_t)(b * 8 + h) * 128 * 1024;    // + d*1024 + s
    const int* mptr = mask + b * 1024;

    // per-lane mask bitmask: bit (t*4+cg) = mask[b][64t + 16cg + r16]
    unsigned long long mbits = 0;
#pragma unroll
    for (int t = 0; t < 16; t++)
#pragma unroll
        for (int cg = 0; cg < 4; cg++)
            mbits |= (unsigned long long)(mptr[t * 64 + cg * 16 + r16] != 0) << (t * 4 + cg);

    f32x4 xacc[8];
#pragma unroll
    for (int i = 0; i < 8; i++) xacc[i] = (f32x4){0.f, 0.f, 0.f, 0.f};
    float mrow[4], lrow[4];
#pragma unroll
    for (int r = 0; r < 4; r++) { mrow[r] = -INFINITY; lrow[r] = 0.f; }

    ushort* Pme = Pl[wid];

    // stage tile t into buffer sel (per wave: 2 K issues + 2 V issues, 16B/lane)
    auto STAGE = [&](int sel, int t) {
        const int kv0 = t * 64;
#pragma unroll
        for (int it = 0; it < 2; ++it) {
            int ob = it * 8192 + wid * 1024;     // wave-uniform LDS byte base
            int o = ob + l * 16;                 // this lane's LDS byte
            int row = o >> 8;                    // kv row 0..63
            int sc = (o & 255) ^ ((row & 7) << 4);
            const ushort* src = Kg + (size_t)(kv0 + row) * 1024 + (sc >> 1);
            __builtin_amdgcn_global_load_lds((const __attribute__((address_space(1))) void*)src,
                (__attribute__((address_space(3))) void*)((char*)&Ks[sel][0] + ob), 16, 0, 0);
        }
#pragma unroll
        for (int it = 0; it < 2; ++it) {
            int ob = it * 8192 + wid * 1024;
            int o = ob + l * 16;
            int d = o >> 7;                      // d row 0..127
            int sc = (o & 127) ^ ((d & 7) << 4);
            const ushort* src = Vg + (size_t)d * 1024 + kv0 + (sc >> 1);
            __builtin_amdgcn_global_load_lds((const __attribute__((address_space(1))) void*)src,
                (__attribute__((address_space(3))) void*)((char*)&Vs[sel][0] + ob), 16, 0, 0);
        }
    };

    STAGE(0, 0);
    int cur = 0;

    for (int t = 0; t < 16; ++t) {
        asm volatile("s_waitcnt vmcnt(0)" ::: "memory");
        __syncthreads();
        if (t < 15) STAGE(cur ^ 1, t + 1);

        const char* Kb_ = (const char*)&Ks[cur][0];
        const char* Vb_ = (const char*)&Vs[cur][0];
        const uint mb4 = (uint)(mbits >> (t * 4)) & 15u;

        // QK^T: s[cg] row=q (g4*4+r), col=kv (cg*16+r16)
        f32x4 s[4];
#pragma unroll
        for (int cg = 0; cg < 4; cg++) {
            s[cg] = (f32x4){0.f, 0.f, 0.f, 0.f};
            const int rowk = cg * 16 + r16;
            const char* kr = Kb_ + rowk * 256;
            const int sw = (rowk & 7) << 4;
#pragma unroll
            for (int kf = 0; kf < 4; kf++) {
                bf16x8 kfr = *(const bf16x8*)(kr + ((kf * 64 + g4 * 16) ^ sw));
                s[cg] = __builtin_amdgcn_mfma_f32_16x16x32_bf16(qf[kf], kfr, s[cg], 0, 0, 0);
            }
            if (!((mb4 >> cg) & 1u)) {
                s[cg][0] = -1e9f; s[cg][1] = -1e9f; s[cg][2] = -1e9f; s[cg][3] = -1e9f;
            }
        }

        // online softmax (rows r spread over g4 groups; reduce over 16 lanes)
        float scl[4];
#pragma unroll
        for (int r = 0; r < 4; r++) {
            float v = fmaxf(fmaxf(s[0][r], s[1][r]), fmaxf(s[2][r], s[3][r]));
            v = fmaxf(v, __shfl_xor(v, 1));
            v = fmaxf(v, __shfl_xor(v, 2));
            v = fmaxf(v, __shfl_xor(v, 4));
            v = fmaxf(v, __shfl_xor(v, 8));
            float mn = fmaxf(mrow[r], v);
            scl[r] = __expf(mrow[r] - mn);
            mrow[r] = mn;
        }
        float rsum[4] = {0.f, 0.f, 0.f, 0.f};
#pragma unroll
        for (int cg = 0; cg < 4; cg++) {
            int col = cg * 16 + r16;
#pragma unroll
            for (int r = 0; r < 4; r++) {
                float p = __expf(s[cg][r] - mrow[r]);
                rsum[r] += p;
                int row = g4 * 4 + r;
                Pme[row * 64 + (col ^ ((row & 7) << 3))] = f2b(p);
            }
        }
#pragma unroll
        for (int r = 0; r < 4; r++) {
            float tt = rsum[r];
            tt += __shfl_xor(tt, 1);
            tt += __shfl_xor(tt, 2);
            tt += __shfl_xor(tt, 4);
            tt += __shfl_xor(tt, 8);
            lrow[r] = lrow[r] * scl[r] + tt;
        }
#pragma unroll
        for (int cg2 = 0; cg2 < 8; cg2++)
#pragma unroll
            for (int r = 0; r < 4; r++) xacc[cg2][r] *= scl[r];

        // PV: A = P[16x64] per-wave, B = V[d][s] (d = n, s = k)
#pragma unroll
        for (int ks = 0; ks < 2; ks++) {
            bf16x8 pfr = *(const bf16x8*)&Pme[r16 * 64 + ((ks * 32 + g4 * 8) ^ ((r16 & 7) << 3))];
#pragma unroll
            for (int cg2 = 0; cg2 < 8; cg2++) {
                const int d = cg2 * 16 + r16;
                bf16x8 vfr = *(const bf16x8*)(Vb_ + d * 128 + ((ks * 64 + g4 * 16) ^ ((d & 7) << 4)));
                xacc[cg2] = __builtin_amdgcn_mfma_f32_16x16x32_bf16(pfr, vfr, xacc[cg2], 0, 0, 0);
            }
        }
        cur ^= 1;
    }

    // write x into xq[:, 0:1024]
#pragma unroll
    for (int cg2 = 0; cg2 < 8; cg2++) {
#pragma unroll
        for (int r = 0; r < 4; r++) {
            float v = xacc[cg2][r] / lrow[r];
            xq[(size_t)(b * 1024 + q0 + g4 * 4 + r) * 2048 + h * 128 + cg2 * 16 + r16] = f2b(v);
        }
    }
}

// ---------------- GLU: out = a * sigmoid(g) ----------------
__global__ __launch_bounds__(256) void glu_kernel(const ushort* __restrict__ z,
                                                  float* __restrict__ out) {
    size_t i = (size_t)blockIdx.x * 1024 + (size_t)threadIdx.x * 4;
    size_t row = i >> 10;
    int c = (int)(i & 1023);
    ushort4 av = *(const ushort4*)&z[row * 2048 + c];
    ushort4 gv = *(const ushort4*)&z[row * 2048 + 1024 + c];
    float4 o;
    o.x = b2f(av.x) * (1.f / (1.f + __expf(-b2f(gv.x))));
    o.y = b2f(av.y) * (1.f / (1.f + __expf(-b2f(gv.y))));
    o.z = b2f(av.z) * (1.f / (1.f + __expf(-b2f(gv.z))));
    o.w = b2f(av.w) * (1.f / (1.f + __expf(-b2f(gv.w))));
    *(float4*)&out[i] = o;
}

extern "C" void kernel_launch(void* const* d_in, const int* in_sizes, int n_in,
                              void* d_out, int out_size, void* d_ws, size_t ws_size,
                              hipStream_t stream) {
    const float* query = (const float*)d_in[0];
    const float* value = (const float*)d_in[1];
    const float* key   = (const float*)d_in[2];
    const int*   mask  = (const int*)d_in[3];
    const float* ln_a  = (const float*)d_in[4];
    const float* ln_b  = (const float*)d_in[5];
    const float* wq    = (const float*)d_in[6];
    const float* bq    = (const float*)d_in[7];
    const float* wk    = (const float*)d_in[8];
    const float* bk    = (const float*)d_in[9];
    const float* wv    = (const float*)d_in[10];
    const float* bv    = (const float*)d_in[11];
    const float* waoa  = (const float*)d_in[12];
    const float* baoa  = (const float*)d_in[13];
    float* out = (float*)d_out;

    char* w8 = (char*)d_ws;
    ushort* xq   = (ushort*)(w8);                 // 8192x2048 bf16 ([x | q_ln])
    ushort* Qb   = (ushort*)(w8 + 33554432);      // 8192x1024 bf16
    ushort* Kb   = (ushort*)(w8 + 50331648);      // 8192x1024 bf16
    ushort* Vt   = (ushort*)(w8 + 67108864);      // (B,H,128,S) bf16
    ushort* keyb = (ushort*)(w8 + 83886080);      // 8192x1024 bf16
    ushort* valb = (ushort*)(w8 + 100663296);     // 8192x1024 bf16
    ushort* zb   = (ushort*)(w8 + 83886080);      // aliases keyb/valb (dead by AOA time)
    ushort* wqb  = (ushort*)(w8 + 117440512);
    ushort* wkb  = (ushort*)(w8 + 119537664);
    ushort* wvb  = (ushort*)(w8 + 121634816);
    ushort* wab  = (ushort*)(w8 + 123731968);     // 2048x2048 bf16

    cast_kernel<<<8192, 256, 0, stream>>>(key, keyb);
    cast_kernel<<<8192, 256, 0, stream>>>(value, valb);
    cast_kernel<<<1024, 256, 0, stream>>>(wq, wqb);
    cast_kernel<<<1024, 256, 0, stream>>>(wk, wkb);
    cast_kernel<<<1024, 256, 0, stream>>>(wv, wvb);
    cast_kernel<<<4096, 256, 0, stream>>>(waoa, wab);
    ln_kernel<<<8192, 256, 0, stream>>>(query, ln_a, ln_b, xq);

    const float qscale = 0.08838834764831845f; // 1/sqrt(128)
    gemm_bt<<<dim3(64, 8), 256, 0, stream>>>(xq + 1024, 2048, wqb, 1024, bq, Qb, 1024, 1024, qscale, 0);
    gemm_bt<<<dim3(64, 8), 256, 0, stream>>>(keyb, 1024, wkb, 1024, bk, Kb, 1024, 1024, 1.f, 0);
    gemm_bt<<<dim3(64, 8), 256, 0, stream>>>(valb, 1024, wvb, 1024, bv, Vt, 0, 1024, 1.f, 1);

    attn_kernel<<<dim3(8, 64), 512, 0, stream>>>(Qb, Kb, Vt, mask, xq);

    gemm_bt<<<dim3(64, 16), 256, 0, stream>>>(xq, 2048, wab, 2048, baoa, zb, 2048, 2048, 1.f, 0);
    glu_kernel<<<8192, 256, 0, stream>>>(zb, out);
}

// Round 3
// 284.793 us; speedup vs baseline: 2.2988x; 1.1500x over previous
//
#include <hip/hip_runtime.h>

typedef __attribute__((ext_vector_type(8))) __bf16 bf16x8;
typedef __attribute__((ext_vector_type(4))) float f32x4;

__device__ __forceinline__ ushort f2b(float f) {
    uint u = __builtin_bit_cast(uint, f);
    u += 0x7fffu + ((u >> 16) & 1u);
    return (ushort)(u >> 16);
}
__device__ __forceinline__ float b2f(ushort h) {
    uint u = ((uint)h) << 16;
    return __builtin_bit_cast(float, u);
}

// ---------------- cast f32 -> bf16 (vec4) ----------------
__global__ __launch_bounds__(256) void cast_kernel(const float* __restrict__ src,
                                                   ushort* __restrict__ dst) {
    size_t i = ((size_t)blockIdx.x * 256 + threadIdx.x) * 4;
    float4 v = *(const float4*)(src + i);
    ushort4 o;
    o.x = f2b(v.x); o.y = f2b(v.y); o.z = f2b(v.z); o.w = f2b(v.w);
    *(ushort4*)(dst + i) = o;
}

// ---------------- LayerNorm(query) -> bf16 into xq[:,1024:2048] ----------------
__global__ __launch_bounds__(256) void ln_kernel(const float* __restrict__ x,
                                                 const float* __restrict__ ga,
                                                 const float* __restrict__ be,
                                                 ushort* __restrict__ xq) {
    const int row = blockIdx.x, tid = threadIdx.x;
    __shared__ float red[4];
    float4 v = ((const float4*)(x + (size_t)row * 1024))[tid];
    float sm = v.x + v.y + v.z + v.w;
    for (int off = 32; off; off >>= 1) sm += __shfl_xor(sm, off);
    if ((tid & 63) == 0) red[tid >> 6] = sm;
    __syncthreads();
    float mean = (red[0] + red[1] + red[2] + red[3]) * (1.f / 1024.f);
    __syncthreads();
    float dx = v.x - mean, dy = v.y - mean, dz = v.z - mean, dw = v.w - mean;
    float s2 = dx * dx + dy * dy + dz * dz + dw * dw;
    for (int off = 32; off; off >>= 1) s2 += __shfl_xor(s2, off);
    if ((tid & 63) == 0) red[tid >> 6] = s2;
    __syncthreads();
    float var = (red[0] + red[1] + red[2] + red[3]) * (1.f / 1023.f);
    float inv = 1.f / (sqrtf(var) + 1e-6f);
    float4 g = ((const float4*)ga)[tid];
    float4 bb = ((const float4*)be)[tid];
    ushort4 o;
    o.x = f2b(g.x * dx * inv + bb.x);
    o.y = f2b(g.y * dy * inv + bb.y);
    o.z = f2b(g.z * dz * inv + bb.z);
    o.w = f2b(g.w * dw * inv + bb.w);
    *(ushort4*)&xq[(size_t)row * 2048 + 1024 + tid * 4] = o;
}

// ---------------- GEMM v2: 128x128 tile, BK=64, T2 swizzle, 2-phase dbuf ----------------
// C[m][n] = (sum_k A[m][k]*B[n][k] + bias[n]) * scale
// A: (M x K) bf16 row-major lda. B: (N x K) bf16 row-major ldb.
// LDS rows are 128B, XOR-swizzled: element c of row r lives at byte 2c ^ ((r&7)<<4).
// global_load_lds dest is linear; the global SOURCE is pre-swizzled (involution).
// mode 0: C bf16 row-major (ldc). mode 1: V-transposed store to Vt (B,H,128,S=1024).
__global__ __launch_bounds__(256) void gemm2(const ushort* __restrict__ A, int lda,
                                             const ushort* __restrict__ B, int ldb,
                                             const float* __restrict__ bias,
                                             ushort* __restrict__ C, int ldc,
                                             int K, int NB, float scale, int mode) {
    __shared__ ushort As[2][8192];
    __shared__ ushort Bs[2][8192];
    const int tid = threadIdx.x;
    const int w = tid >> 6, l = tid & 63;
    const int wr = w >> 1, wc = w & 1;
    const int r16 = l & 15, g4 = l >> 4;

    // T1: XCD-aware swizzle (grid sizes are multiples of 8)
    const int bid = blockIdx.x;
    const int cpx = gridDim.x >> 3;
    const int swz = (bid & 7) * cpx + (bid >> 3);
    const int m0 = (swz / NB) * 128;
    const int n0 = (swz % NB) * 128;

    // staging geometry: issue 'it' covers rows (it*4+w)*8 + (l>>3); the lane's
    // 16B source chunk within the row is pre-swizzled by the inverse XOR.
    const int srow = l >> 3;                       // 0..7
    const int scol = ((l & 7) ^ srow) * 8;         // element offset in row
    const ushort* Asrc = A + (size_t)(m0 + w * 8 + srow) * lda + scol;
    const ushort* Bsrc = B + (size_t)(n0 + w * 8 + srow) * ldb + scol;

    f32x4 acc[4][4];
#pragma unroll
    for (int i = 0; i < 4; i++)
#pragma unroll
        for (int j = 0; j < 4; j++) acc[i][j] = (f32x4){0.f, 0.f, 0.f, 0.f};

    auto STAGE = [&](int sel, int kt) {
#pragma unroll
        for (int it = 0; it < 4; it++) {
            __builtin_amdgcn_global_load_lds(
                (const __attribute__((address_space(1))) void*)(Asrc + (size_t)(it * 32) * lda + kt * 64),
                (__attribute__((address_space(3))) void*)(&As[sel][(it * 4 + w) * 512]), 16, 0, 0);
            __builtin_amdgcn_global_load_lds(
                (const __attribute__((address_space(1))) void*)(Bsrc + (size_t)(it * 32) * ldb + kt * 64),
                (__attribute__((address_space(3))) void*)(&Bs[sel][(it * 4 + w) * 512]), 16, 0, 0);
        }
    };

    const int swzr = (g4 ^ (r16 & 7)) << 4;   // swizzled 16B slot for fragment reads

    auto COMPUTE = [&](int sel, int kt, bool stage_next) {
        if (stage_next) STAGE(sel ^ 1, kt + 1);
        const char* Ab = (const char*)&As[sel][0];
        const char* Bb = (const char*)&Bs[sel][0];
        bf16x8 af[4][2], bfv[4][2];
#pragma unroll
        for (int mi = 0; mi < 4; mi++) {
            int ba = (wr * 64 + mi * 16 + r16) * 128 + swzr;
            af[mi][0] = *(const bf16x8*)(Ab + ba);
            af[mi][1] = *(const bf16x8*)(Ab + (ba ^ 64));   // ks=1 slot
        }
#pragma unroll
        for (int ni = 0; ni < 4; ni++) {
            int bb = (wc * 64 + ni * 16 + r16) * 128 + swzr;
            bfv[ni][0] = *(const bf16x8*)(Bb + bb);
            bfv[ni][1] = *(const bf16x8*)(Bb + (bb ^ 64));
        }
        __builtin_amdgcn_s_setprio(1);
#pragma unroll
        for (int ks = 0; ks < 2; ks++)
#pragma unroll
            for (int mi = 0; mi < 4; mi++)
#pragma unroll
                for (int ni = 0; ni < 4; ni++)
                    acc[mi][ni] = __builtin_amdgcn_mfma_f32_16x16x32_bf16(af[mi][ks], bfv[ni][ks], acc[mi][ni], 0, 0, 0);
        __builtin_amdgcn_s_setprio(0);
        asm volatile("s_waitcnt vmcnt(0)" ::: "memory");   // prefetch landed
        __syncthreads();
    };

    STAGE(0, 0);
    asm volatile("s_waitcnt vmcnt(0)" ::: "memory");
    __syncthreads();
    const int NT = K >> 6;   // K is a multiple of 128 -> NT even
    for (int kt = 0; kt < NT; kt += 2) {
        COMPUTE(0, kt, true);
        COMPUTE(1, kt + 1, kt + 2 < NT);
    }

    const int row0 = m0 + wr * 64;
    const int col0 = n0 + wc * 64;
    if (mode == 0) {
#pragma unroll
        for (int ni = 0; ni < 4; ni++) {
            int n = col0 + ni * 16 + r16;
            float bs = bias[n];
#pragma unroll
            for (int mi = 0; mi < 4; mi++) {
                int mr = row0 + mi * 16 + g4 * 4;
#pragma unroll
                for (int r = 0; r < 4; r++) {
                    C[(size_t)(mr + r) * ldc + n] = f2b((acc[mi][ni][r] + bs) * scale);
                }
            }
        }
    } else {
        // Vt[(b*8+h)*128 + d][s], m = b*1024+s, n = h*128+d
#pragma unroll
        for (int ni = 0; ni < 4; ni++) {
            int n = col0 + ni * 16 + r16;
            float bs = bias[n];
            int h = n >> 7, d = n & 127;
#pragma unroll
            for (int mi = 0; mi < 4; mi++) {
                int m = row0 + mi * 16 + g4 * 4;
                int b_ = m >> 10, s_ = m & 1023;
                ushort4 o;
                o.x = f2b((acc[mi][ni][0] + bs) * scale);
                o.y = f2b((acc[mi][ni][1] + bs) * scale);
                o.z = f2b((acc[mi][ni][2] + bs) * scale);
                o.w = f2b((acc[mi][ni][3] + bs) * scale);
                *(ushort4*)&C[((size_t)(b_ * 8 + h) * 128 + d) * 1024 + s_] = o;
            }
        }
    }
}

// ---------------- flash attention (8 waves, QBLK=128, KVBLK=64, LDS dbuf) ----------------
__global__ __launch_bounds__(512, 4) void attn_kernel(const ushort* __restrict__ Q,
                                                      const ushort* __restrict__ Kt,
                                                      const ushort* __restrict__ Vt,
                                                      const int* __restrict__ mask,
                                                      ushort* __restrict__ xq) {
    __shared__ ushort Ks[2][8192];   // [64 kv][128 d], row=256B, XOR swz ((row&7)<<4 bytes)
    __shared__ ushort Vs[2][8192];   // [128 d][64 s],  row=128B, XOR swz ((d&7)<<4 bytes)
    __shared__ ushort Pl[8][1024];   // per-wave [16 q][64 kv], XOR swz ((row&7)<<3 elems)

    const int tid = threadIdx.x;
    const int l = tid & 63, wid = tid >> 6;
    const int r16 = l & 15, g4 = l >> 4;
    const int bh = blockIdx.y;
    const int b = bh >> 3, h = bh & 7;
    const int q0 = blockIdx.x * 128 + wid * 16;

    bf16x8 qf[4];
    const ushort* Qrow = Q + (size_t)(b * 1024 + q0 + r16) * 1024 + h * 128 + g4 * 8;
#pragma unroll
    for (int kf = 0; kf < 4; kf++) qf[kf] = *(const bf16x8*)(Qrow + kf * 32);

    const ushort* Kg = Kt + ((size_t)b * 1024) * 1024 + h * 128; // + s*1024 + d
    const ushort* Vg = Vt + (size_t)(b * 8 + h) * 128 * 1024;    // + d*1024 + s
    const int* mptr = mask + b * 1024;

    unsigned long long mbits = 0;
#pragma unroll
    for (int t = 0; t < 16; t++)
#pragma unroll
        for (int cg = 0; cg < 4; cg++)
            mbits |= (unsigned long long)(mptr[t * 64 + cg * 16 + r16] != 0) << (t * 4 + cg);

    f32x4 xacc[8];
#pragma unroll
    for (int i = 0; i < 8; i++) xacc[i] = (f32x4){0.f, 0.f, 0.f, 0.f};
    float mrow[4], lrow[4];
#pragma unroll
    for (int r = 0; r < 4; r++) { mrow[r] = -INFINITY; lrow[r] = 0.f; }

    ushort* Pme = Pl[wid];

    auto STAGE = [&](int sel, int t) {
        const int kv0 = t * 64;
#pragma unroll
        for (int it = 0; it < 2; ++it) {
            int ob = it * 8192 + wid * 1024;
            int o = ob + l * 16;
            int row = o >> 8;
            int sc = (o & 255) ^ ((row & 7) << 4);
            const ushort* src = Kg + (size_t)(kv0 + row) * 1024 + (sc >> 1);
            __builtin_amdgcn_global_load_lds((const __attribute__((address_space(1))) void*)src,
                (__attribute__((address_space(3))) void*)((char*)&Ks[sel][0] + ob), 16, 0, 0);
        }
#pragma unroll
        for (int it = 0; it < 2; ++it) {
            int ob = it * 8192 + wid * 1024;
            int o = ob + l * 16;
            int d = o >> 7;
            int sc = (o & 127) ^ ((d & 7) << 4);
            const ushort* src = Vg + (size_t)d * 1024 + kv0 + (sc >> 1);
            __builtin_amdgcn_global_load_lds((const __attribute__((address_space(1))) void*)src,
                (__attribute__((address_space(3))) void*)((char*)&Vs[sel][0] + ob), 16, 0, 0);
        }
    };

    STAGE(0, 0);
    int cur = 0;

    for (int t = 0; t < 16; ++t) {
        asm volatile("s_waitcnt vmcnt(0)" ::: "memory");
        __syncthreads();
        if (t < 15) STAGE(cur ^ 1, t + 1);

        const char* Kb_ = (const char*)&Ks[cur][0];
        const char* Vb_ = (const char*)&Vs[cur][0];
        const uint mb4 = (uint)(mbits >> (t * 4)) & 15u;

        f32x4 s[4];
#pragma unroll
        for (int cg = 0; cg < 4; cg++) {
            s[cg] = (f32x4){0.f, 0.f, 0.f, 0.f};
            const int rowk = cg * 16 + r16;
            const char* kr = Kb_ + rowk * 256;
            const int sw = (rowk & 7) << 4;
#pragma unroll
            for (int kf = 0; kf < 4; kf++) {
                bf16x8 kfr = *(const bf16x8*)(kr + ((kf * 64 + g4 * 16) ^ sw));
                s[cg] = __builtin_amdgcn_mfma_f32_16x16x32_bf16(qf[kf], kfr, s[cg], 0, 0, 0);
            }
            if (!((mb4 >> cg) & 1u)) {
                s[cg][0] = -1e9f; s[cg][1] = -1e9f; s[cg][2] = -1e9f; s[cg][3] = -1e9f;
            }
        }

        float scl[4];
#pragma unroll
        for (int r = 0; r < 4; r++) {
            float v = fmaxf(fmaxf(s[0][r], s[1][r]), fmaxf(s[2][r], s[3][r]));
            v = fmaxf(v, __shfl_xor(v, 1));
            v = fmaxf(v, __shfl_xor(v, 2));
            v = fmaxf(v, __shfl_xor(v, 4));
            v = fmaxf(v, __shfl_xor(v, 8));
            float mn = fmaxf(mrow[r], v);
            scl[r] = __expf(mrow[r] - mn);
            mrow[r] = mn;
        }
        float rsum[4] = {0.f, 0.f, 0.f, 0.f};
#pragma unroll
        for (int cg = 0; cg < 4; cg++) {
            int col = cg * 16 + r16;
#pragma unroll
            for (int r = 0; r < 4; r++) {
                float p = __expf(s[cg][r] - mrow[r]);
                rsum[r] += p;
                int row = g4 * 4 + r;
                Pme[row * 64 + (col ^ ((row & 7) << 3))] = f2b(p);
            }
        }
#pragma unroll
        for (int r = 0; r < 4; r++) {
            float tt = rsum[r];
            tt += __shfl_xor(tt, 1);
            tt += __shfl_xor(tt, 2);
            tt += __shfl_xor(tt, 4);
            tt += __shfl_xor(tt, 8);
            lrow[r] = lrow[r] * scl[r] + tt;
        }
#pragma unroll
        for (int cg2 = 0; cg2 < 8; cg2++)
#pragma unroll
            for (int r = 0; r < 4; r++) xacc[cg2][r] *= scl[r];

#pragma unroll
        for (int ks = 0; ks < 2; ks++) {
            bf16x8 pfr = *(const bf16x8*)&Pme[r16 * 64 + ((ks * 32 + g4 * 8) ^ ((r16 & 7) << 3))];
#pragma unroll
            for (int cg2 = 0; cg2 < 8; cg2++) {
                const int d = cg2 * 16 + r16;
                bf16x8 vfr = *(const bf16x8*)(Vb_ + d * 128 + ((ks * 64 + g4 * 16) ^ ((d & 7) << 4)));
                xacc[cg2] = __builtin_amdgcn_mfma_f32_16x16x32_bf16(pfr, vfr, xacc[cg2], 0, 0, 0);
            }
        }
        cur ^= 1;
    }

#pragma unroll
    for (int cg2 = 0; cg2 < 8; cg2++) {
#pragma unroll
        for (int r = 0; r < 4; r++) {
            float v = xacc[cg2][r] / lrow[r];
            xq[(size_t)(b * 1024 + q0 + g4 * 4 + r) * 2048 + h * 128 + cg2 * 16 + r16] = f2b(v);
        }
    }
}

// ---------------- GLU: out = a * sigmoid(g) ----------------
__global__ __launch_bounds__(256) void glu_kernel(const ushort* __restrict__ z,
                                                  float* __restrict__ out) {
    size_t i = (size_t)blockIdx.x * 1024 + (size_t)threadIdx.x * 4;
    size_t row = i >> 10;
    int c = (int)(i & 1023);
    ushort4 av = *(const ushort4*)&z[row * 2048 + c];
    ushort4 gv = *(const ushort4*)&z[row * 2048 + 1024 + c];
    float4 o;
    o.x = b2f(av.x) * (1.f / (1.f + __expf(-b2f(gv.x))));
    o.y = b2f(av.y) * (1.f / (1.f + __expf(-b2f(gv.y))));
    o.z = b2f(av.z) * (1.f / (1.f + __expf(-b2f(gv.z))));
    o.w = b2f(av.w) * (1.f / (1.f + __expf(-b2f(gv.w))));
    *(float4*)&out[i] = o;
}

extern "C" void kernel_launch(void* const* d_in, const int* in_sizes, int n_in,
                              void* d_out, int out_size, void* d_ws, size_t ws_size,
                              hipStream_t stream) {
    const float* query = (const float*)d_in[0];
    const float* value = (const float*)d_in[1];
    const float* key   = (const float*)d_in[2];
    const int*   mask  = (const int*)d_in[3];
    const float* ln_a  = (const float*)d_in[4];
    const float* ln_b  = (const float*)d_in[5];
    const float* wq    = (const float*)d_in[6];
    const float* bq    = (const float*)d_in[7];
    const float* wk    = (const float*)d_in[8];
    const float* bk    = (const float*)d_in[9];
    const float* wv    = (const float*)d_in[10];
    const float* bv    = (const float*)d_in[11];
    const float* waoa  = (const float*)d_in[12];
    const float* baoa  = (const float*)d_in[13];
    float* out = (float*)d_out;

    char* w8 = (char*)d_ws;
    ushort* xq   = (ushort*)(w8);                 // 8192x2048 bf16 ([x | q_ln])
    ushort* Qb   = (ushort*)(w8 + 33554432);      // 8192x1024 bf16
    ushort* Kb   = (ushort*)(w8 + 50331648);      // 8192x1024 bf16
    ushort* Vt   = (ushort*)(w8 + 67108864);      // (B,H,128,S) bf16
    ushort* keyb = (ushort*)(w8 + 83886080);      // 8192x1024 bf16
    ushort* valb = (ushort*)(w8 + 100663296);     // 8192x1024 bf16
    ushort* zb   = (ushort*)(w8 + 83886080);      // aliases keyb/valb (dead by AOA time)
    ushort* wqb  = (ushort*)(w8 + 117440512);
    ushort* wkb  = (ushort*)(w8 + 119537664);
    ushort* wvb  = (ushort*)(w8 + 121634816);
    ushort* wab  = (ushort*)(w8 + 123731968);     // 2048x2048 bf16

    cast_kernel<<<8192, 256, 0, stream>>>(key, keyb);
    cast_kernel<<<8192, 256, 0, stream>>>(value, valb);
    cast_kernel<<<1024, 256, 0, stream>>>(wq, wqb);
    cast_kernel<<<1024, 256, 0, stream>>>(wk, wkb);
    cast_kernel<<<1024, 256, 0, stream>>>(wv, wvb);
    cast_kernel<<<4096, 256, 0, stream>>>(waoa, wab);
    ln_kernel<<<8192, 256, 0, stream>>>(query, ln_a, ln_b, xq);

    const float qscale = 0.08838834764831845f; // 1/sqrt(128)
    gemm2<<<512, 256, 0, stream>>>(xq + 1024, 2048, wqb, 1024, bq, Qb, 1024, 1024, 8, qscale, 0);
    gemm2<<<512, 256, 0, stream>>>(keyb, 1024, wkb, 1024, bk, Kb, 1024, 1024, 8, 1.f, 0);
    gemm2<<<512, 256, 0, stream>>>(valb, 1024, wvb, 1024, bv, Vt, 0, 1024, 8, 1.f, 1);

    attn_kernel<<<dim3(8, 64), 512, 0, stream>>>(Qb, Kb, Vt, mask, xq);

    gemm2<<<1024, 256, 0, stream>>>(xq, 2048, wab, 2048, baoa, zb, 2048, 2048, 16, 1.f, 0);
    glu_kernel<<<8192, 256, 0, stream>>>(zb, out);
}

// Round 4
// 272.367 us; speedup vs baseline: 2.4037x; 1.0456x over previous
//
#include <hip/hip_runtime.h>

typedef __attribute__((ext_vector_type(8))) __bf16 bf16x8;
typedef __attribute__((ext_vector_type(4))) float f32x4;

__device__ __forceinline__ ushort f2b(float f) {
    uint u = __builtin_bit_cast(uint, f);
    u += 0x7fffu + ((u >> 16) & 1u);
    return (ushort)(u >> 16);
}
__device__ __forceinline__ float b2f(ushort h) {
    uint u = ((uint)h) << 16;
    return __builtin_bit_cast(float, u);
}

// ---------------- cast f32 -> bf16 (vec4) ----------------
__global__ __launch_bounds__(256) void cast_kernel(const float* __restrict__ src,
                                                   ushort* __restrict__ dst) {
    size_t i = ((size_t)blockIdx.x * 256 + threadIdx.x) * 4;
    float4 v = *(const float4*)(src + i);
    ushort4 o;
    o.x = f2b(v.x); o.y = f2b(v.y); o.z = f2b(v.z); o.w = f2b(v.w);
    *(ushort4*)(dst + i) = o;
}

// ---------------- LayerNorm(query) -> bf16 into xq[:,1024:2048] ----------------
__global__ __launch_bounds__(256) void ln_kernel(const float* __restrict__ x,
                                                 const float* __restrict__ ga,
                                                 const float* __restrict__ be,
                                                 ushort* __restrict__ xq) {
    const int row = blockIdx.x, tid = threadIdx.x;
    __shared__ float red[4];
    float4 v = ((const float4*)(x + (size_t)row * 1024))[tid];
    float sm = v.x + v.y + v.z + v.w;
    for (int off = 32; off; off >>= 1) sm += __shfl_xor(sm, off);
    if ((tid & 63) == 0) red[tid >> 6] = sm;
    __syncthreads();
    float mean = (red[0] + red[1] + red[2] + red[3]) * (1.f / 1024.f);
    __syncthreads();
    float dx = v.x - mean, dy = v.y - mean, dz = v.z - mean, dw = v.w - mean;
    float s2 = dx * dx + dy * dy + dz * dz + dw * dw;
    for (int off = 32; off; off >>= 1) s2 += __shfl_xor(s2, off);
    if ((tid & 63) == 0) red[tid >> 6] = s2;
    __syncthreads();
    float var = (red[0] + red[1] + red[2] + red[3]) * (1.f / 1023.f);
    float inv = 1.f / (sqrtf(var) + 1e-6f);
    float4 g = ((const float4*)ga)[tid];
    float4 bb = ((const float4*)be)[tid];
    ushort4 o;
    o.x = f2b(g.x * dx * inv + bb.x);
    o.y = f2b(g.y * dy * inv + bb.y);
    o.z = f2b(g.z * dz * inv + bb.z);
    o.w = f2b(g.w * dw * inv + bb.w);
    *(ushort4*)&xq[(size_t)row * 2048 + 1024 + tid * 4] = o;
}

// ---------------- GEMM v2: 128x128 tile, BK=64, T2 swizzle, 2-phase dbuf ----------------
__global__ __launch_bounds__(256) void gemm2(const ushort* __restrict__ A, int lda,
                                             const ushort* __restrict__ B, int ldb,
                                             const float* __restrict__ bias,
                                             ushort* __restrict__ C, int ldc,
                                             int K, int NB, float scale, int mode) {
    __shared__ ushort As[2][8192];
    __shared__ ushort Bs[2][8192];
    const int tid = threadIdx.x;
    const int w = tid >> 6, l = tid & 63;
    const int wr = w >> 1, wc = w & 1;
    const int r16 = l & 15, g4 = l >> 4;

    const int bid = blockIdx.x;
    const int cpx = gridDim.x >> 3;
    const int swz = (bid & 7) * cpx + (bid >> 3);
    const int m0 = (swz / NB) * 128;
    const int n0 = (swz % NB) * 128;

    const int srow = l >> 3;
    const int scol = ((l & 7) ^ srow) * 8;
    const ushort* Asrc = A + (size_t)(m0 + w * 8 + srow) * lda + scol;
    const ushort* Bsrc = B + (size_t)(n0 + w * 8 + srow) * ldb + scol;

    f32x4 acc[4][4];
#pragma unroll
    for (int i = 0; i < 4; i++)
#pragma unroll
        for (int j = 0; j < 4; j++) acc[i][j] = (f32x4){0.f, 0.f, 0.f, 0.f};

    auto STAGE = [&](int sel, int kt) {
#pragma unroll
        for (int it = 0; it < 4; it++) {
            __builtin_amdgcn_global_load_lds(
                (const __attribute__((address_space(1))) void*)(Asrc + (size_t)(it * 32) * lda + kt * 64),
                (__attribute__((address_space(3))) void*)(&As[sel][(it * 4 + w) * 512]), 16, 0, 0);
            __builtin_amdgcn_global_load_lds(
                (const __attribute__((address_space(1))) void*)(Bsrc + (size_t)(it * 32) * ldb + kt * 64),
                (__attribute__((address_space(3))) void*)(&Bs[sel][(it * 4 + w) * 512]), 16, 0, 0);
        }
    };

    const int swzr = (g4 ^ (r16 & 7)) << 4;

    auto COMPUTE = [&](int sel, int kt, bool stage_next) {
        if (stage_next) STAGE(sel ^ 1, kt + 1);
        const char* Ab = (const char*)&As[sel][0];
        const char* Bb = (const char*)&Bs[sel][0];
        bf16x8 af[4][2], bfv[4][2];
#pragma unroll
        for (int mi = 0; mi < 4; mi++) {
            int ba = (wr * 64 + mi * 16 + r16) * 128 + swzr;
            af[mi][0] = *(const bf16x8*)(Ab + ba);
            af[mi][1] = *(const bf16x8*)(Ab + (ba ^ 64));
        }
#pragma unroll
        for (int ni = 0; ni < 4; ni++) {
            int bb = (wc * 64 + ni * 16 + r16) * 128 + swzr;
            bfv[ni][0] = *(const bf16x8*)(Bb + bb);
            bfv[ni][1] = *(const bf16x8*)(Bb + (bb ^ 64));
        }
        __builtin_amdgcn_s_setprio(1);
#pragma unroll
        for (int ks = 0; ks < 2; ks++)
#pragma unroll
            for (int mi = 0; mi < 4; mi++)
#pragma unroll
                for (int ni = 0; ni < 4; ni++)
                    acc[mi][ni] = __builtin_amdgcn_mfma_f32_16x16x32_bf16(af[mi][ks], bfv[ni][ks], acc[mi][ni], 0, 0, 0);
        __builtin_amdgcn_s_setprio(0);
        asm volatile("s_waitcnt vmcnt(0)" ::: "memory");
        __syncthreads();
    };

    STAGE(0, 0);
    asm volatile("s_waitcnt vmcnt(0)" ::: "memory");
    __syncthreads();
    const int NT = K >> 6;
    for (int kt = 0; kt < NT; kt += 2) {
        COMPUTE(0, kt, true);
        COMPUTE(1, kt + 1, kt + 2 < NT);
    }

    const int row0 = m0 + wr * 64;
    const int col0 = n0 + wc * 64;
    if (mode == 0) {
#pragma unroll
        for (int ni = 0; ni < 4; ni++) {
            int n = col0 + ni * 16 + r16;
            float bs = bias[n];
#pragma unroll
            for (int mi = 0; mi < 4; mi++) {
                int mr = row0 + mi * 16 + g4 * 4;
#pragma unroll
                for (int r = 0; r < 4; r++) {
                    C[(size_t)(mr + r) * ldc + n] = f2b((acc[mi][ni][r] + bs) * scale);
                }
            }
        }
    } else {
#pragma unroll
        for (int ni = 0; ni < 4; ni++) {
            int n = col0 + ni * 16 + r16;
            float bs = bias[n];
            int h = n >> 7, d = n & 127;
#pragma unroll
            for (int mi = 0; mi < 4; mi++) {
                int m = row0 + mi * 16 + g4 * 4;
                int b_ = m >> 10, s_ = m & 1023;
                ushort4 o;
                o.x = f2b((acc[mi][ni][0] + bs) * scale);
                o.y = f2b((acc[mi][ni][1] + bs) * scale);
                o.z = f2b((acc[mi][ni][2] + bs) * scale);
                o.w = f2b((acc[mi][ni][3] + bs) * scale);
                *(ushort4*)&C[((size_t)(b_ * 8 + h) * 128 + d) * 1024 + s_] = o;
            }
        }
    }
}

// ---------------- flash attention v3: swapped-operand (S^T / x^T), lane-local softmax ----------------
// Block = (b,h) x 128 q-rows, 8 waves x 16 q-rows. Grid 1D 512, mapped so the
// 8 q-blocks of one (b,h) share an XCD (ids congruent mod 8).
// QK^T = mfma(K,Q) -> lane holds S^T[kv=cg*16+g4*4+r][q=r16]: row softmax is
// 15 in-reg ops + 2 shfl. PV = mfma(V,P) -> x^T, rescale/divide lane-local.
// Mask via per-tile wave-uniform __ballot (SGPR), 1 prefetched int/lane/iter.
__global__ __launch_bounds__(512, 4) void attn_kernel(const ushort* __restrict__ Q,
                                                      const ushort* __restrict__ Kt,
                                                      const ushort* __restrict__ Vt,
                                                      const int* __restrict__ mask,
                                                      ushort* __restrict__ xq) {
    __shared__ ushort Ks[2][8192];   // [64 kv][128 d], row=256B, XOR swz ((row&7)<<4 bytes)
    __shared__ ushort Vs[2][8192];   // [128 d][64 s],  row=128B, XOR swz ((d&7)<<4 bytes)
    __shared__ ushort Pl[8][1024];   // per-wave [16 q][64 kv], 128B rows, XOR swz ((q&7)<<4 bytes)

    const int tid = threadIdx.x;
    const int l = tid & 63, wid = tid >> 6;
    const int r16 = l & 15, g4 = l >> 4;
    const int id = blockIdx.x;
    const int bh = ((id >> 6) << 3) | (id & 7);   // same-bh blocks differ by 8 -> same XCD
    const int qb = (id >> 3) & 7;
    const int b = bh >> 3, h = bh & 7;
    const int q0 = qb * 128 + wid * 16;

    bf16x8 qf[4];
    const ushort* Qrow = Q + (size_t)(b * 1024 + q0 + r16) * 1024 + h * 128 + g4 * 8;
#pragma unroll
    for (int kf = 0; kf < 4; kf++) qf[kf] = *(const bf16x8*)(Qrow + kf * 32);

    const ushort* Kg = Kt + ((size_t)b * 1024) * 1024 + h * 128; // + s*1024 + d
    const ushort* Vg = Vt + (size_t)(b * 8 + h) * 128 * 1024;    // + d*1024 + s
    const int* mptr = mask + b * 1024;
    int mv = mptr[l];   // tile-0 mask element for this lane

    f32x4 xacc[8];
#pragma unroll
    for (int i = 0; i < 8; i++) xacc[i] = (f32x4){0.f, 0.f, 0.f, 0.f};
    float mrow = -INFINITY, lrow = 0.f;   // running (m,l) for q = q0 + r16

    char* Pme = (char*)&Pl[wid][0];
    const int pswz = (r16 & 7) << 4;

    auto STAGE = [&](int sel, int t) {
        const int kv0 = t * 64;
#pragma unroll
        for (int it = 0; it < 2; ++it) {
            int ob = it * 8192 + wid * 1024;
            int o = ob + l * 16;
            int row = o >> 8;
            int sc = (o & 255) ^ ((row & 7) << 4);
            const ushort* src = Kg + (size_t)(kv0 + row) * 1024 + (sc >> 1);
            __builtin_amdgcn_global_load_lds((const __attribute__((address_space(1))) void*)src,
                (__attribute__((address_space(3))) void*)((char*)&Ks[sel][0] + ob), 16, 0, 0);
        }
#pragma unroll
        for (int it = 0; it < 2; ++it) {
            int ob = it * 8192 + wid * 1024;
            int o = ob + l * 16;
            int d = o >> 7;
            int sc = (o & 127) ^ ((d & 7) << 4);
            const ushort* src = Vg + (size_t)d * 1024 + kv0 + (sc >> 1);
            __builtin_amdgcn_global_load_lds((const __attribute__((address_space(1))) void*)src,
                (__attribute__((address_space(3))) void*)((char*)&Vs[sel][0] + ob), 16, 0, 0);
        }
    };

    STAGE(0, 0);
    int cur = 0;

    for (int t = 0; t < 16; ++t) {
        int mvn = (t < 15) ? mptr[(t + 1) * 64 + l] : 0;      // prefetch next tile's mask
        unsigned long long wt = __ballot(mv != 0);            // bit kv&63 -> SGPR

        asm volatile("s_waitcnt vmcnt(0)" ::: "memory");
        __syncthreads();
        if (t < 15) STAGE(cur ^ 1, t + 1);

        const char* Kb_ = (const char*)&Ks[cur][0];
        const char* Vb_ = (const char*)&Vs[cur][0];

        // S^T: s[cg][r] = S[kv = cg*16 + g4*4 + r][q = r16]
        f32x4 s[4];
#pragma unroll
        for (int cg = 0; cg < 4; cg++) {
            s[cg] = (f32x4){0.f, 0.f, 0.f, 0.f};
            const int rowk = cg * 16 + r16;
            const char* kr = Kb_ + rowk * 256;
            const int sw = (rowk & 7) << 4;
#pragma unroll
            for (int kf = 0; kf < 4; kf++) {
                bf16x8 kfr = *(const bf16x8*)(kr + ((kf * 64 + g4 * 16) ^ sw));
                s[cg] = __builtin_amdgcn_mfma_f32_16x16x32_bf16(kfr, qf[kf], s[cg], 0, 0, 0);
            }
            uint nib = (uint)(wt >> (cg * 16 + g4 * 4)) & 15u;
#pragma unroll
            for (int r = 0; r < 4; r++)
                if (!((nib >> r) & 1u)) s[cg][r] = -1e9f;
        }

        // lane-local row softmax (q = r16): 16 in-reg values + 2 shfl
        float pmax = -INFINITY;
#pragma unroll
        for (int cg = 0; cg < 4; cg++)
#pragma unroll
            for (int r = 0; r < 4; r++) pmax = fmaxf(pmax, s[cg][r]);
        pmax = fmaxf(pmax, __shfl_xor(pmax, 16));
        pmax = fmaxf(pmax, __shfl_xor(pmax, 32));
        float mn = fmaxf(mrow, pmax);
        float scl = __expf(mrow - mn);
        mrow = mn;

        float rsum = 0.f;
#pragma unroll
        for (int cg = 0; cg < 4; cg++)
#pragma unroll
            for (int r = 0; r < 4; r++) {
                float p = __expf(s[cg][r] - mn);
                s[cg][r] = p;
                rsum += p;
            }
        rsum += __shfl_xor(rsum, 16);
        rsum += __shfl_xor(rsum, 32);
        lrow = lrow * scl + rsum;

        // pack P row (q=r16): 4x ds_write_b64, swizzled
#pragma unroll
        for (int cg = 0; cg < 4; cg++) {
            uint lo = ((uint)f2b(s[cg][1]) << 16) | f2b(s[cg][0]);
            uint hi = ((uint)f2b(s[cg][3]) << 16) | f2b(s[cg][2]);
            uint2 pk; pk.x = lo; pk.y = hi;
            *(uint2*)(Pme + r16 * 128 + ((cg * 32 + g4 * 8) ^ pswz)) = pk;
        }

        // rescale previous accumulator (scl is lane-local: q = r16)
#pragma unroll
        for (int cg2 = 0; cg2 < 8; cg2++)
#pragma unroll
            for (int r = 0; r < 4; r++) xacc[cg2][r] *= scl;

        // x^T += mfma(V, P): A = V rows d, B = P^T cols q
#pragma unroll
        for (int ks = 0; ks < 2; ks++) {
            bf16x8 pfr = *(const bf16x8*)(Pme + r16 * 128 + ((g4 * 16 + ks * 64) ^ pswz));
#pragma unroll
            for (int cg2 = 0; cg2 < 8; cg2++) {
                const int d = cg2 * 16 + r16;
                bf16x8 vfr = *(const bf16x8*)(Vb_ + d * 128 + ((ks * 64 + g4 * 16) ^ ((d & 7) << 4)));
                xacc[cg2] = __builtin_amdgcn_mfma_f32_16x16x32_bf16(vfr, pfr, xacc[cg2], 0, 0, 0);
            }
        }
        mv = mvn;
        cur ^= 1;
    }

    // write x^T: lane holds x[q = q0+r16][d = cg2*16 + g4*4 + r] / lrow
    const float inv = 1.f / lrow;
    const size_t orow = (size_t)(b * 1024 + q0 + r16) * 2048 + h * 128;
#pragma unroll
    for (int cg2 = 0; cg2 < 8; cg2++) {
#pragma unroll
        for (int r = 0; r < 4; r++) {
            xq[orow + cg2 * 16 + g4 * 4 + r] = f2b(xacc[cg2][r] * inv);
        }
    }
}

// ---------------- GLU: out = a * sigmoid(g) ----------------
__global__ __launch_bounds__(256) void glu_kernel(const ushort* __restrict__ z,
                                                  float* __restrict__ out) {
    size_t i = (size_t)blockIdx.x * 1024 + (size_t)threadIdx.x * 4;
    size_t row = i >> 10;
    int c = (int)(i & 1023);
    ushort4 av = *(const ushort4*)&z[row * 2048 + c];
    ushort4 gv = *(const ushort4*)&z[row * 2048 + 1024 + c];
    float4 o;
    o.x = b2f(av.x) * (1.f / (1.f + __expf(-b2f(gv.x))));
    o.y = b2f(av.y) * (1.f / (1.f + __expf(-b2f(gv.y))));
    o.z = b2f(av.z) * (1.f / (1.f + __expf(-b2f(gv.z))));
    o.w = b2f(av.w) * (1.f / (1.f + __expf(-b2f(gv.w))));
    *(float4*)&out[i] = o;
}

extern "C" void kernel_launch(void* const* d_in, const int* in_sizes, int n_in,
                              void* d_out, int out_size, void* d_ws, size_t ws_size,
                              hipStream_t stream) {
    const float* query = (const float*)d_in[0];
    const float* value = (const float*)d_in[1];
    const float* key   = (const float*)d_in[2];
    const int*   mask  = (const int*)d_in[3];
    const float* ln_a  = (const float*)d_in[4];
    const float* ln_b  = (const float*)d_in[5];
    const float* wq    = (const float*)d_in[6];
    const float* bq    = (const float*)d_in[7];
    const float* wk    = (const float*)d_in[8];
    const float* bk    = (const float*)d_in[9];
    const float* wv    = (const float*)d_in[10];
    const float* bv    = (const float*)d_in[11];
    const float* waoa  = (const float*)d_in[12];
    const float* baoa  = (const float*)d_in[13];
    float* out = (float*)d_out;

    char* w8 = (char*)d_ws;
    ushort* xq   = (ushort*)(w8);                 // 8192x2048 bf16 ([x | q_ln])
    ushort* Qb   = (ushort*)(w8 + 33554432);      // 8192x1024 bf16
    ushort* Kb   = (ushort*)(w8 + 50331648);      // 8192x1024 bf16
    ushort* Vt   = (ushort*)(w8 + 67108864);      // (B,H,128,S) bf16
    ushort* keyb = (ushort*)(w8 + 83886080);      // 8192x1024 bf16
    ushort* valb = (ushort*)(w8 + 100663296);     // 8192x1024 bf16
    ushort* zb   = (ushort*)(w8 + 83886080);      // aliases keyb/valb (dead by AOA time)
    ushort* wqb  = (ushort*)(w8 + 117440512);
    ushort* wkb  = (ushort*)(w8 + 119537664);
    ushort* wvb  = (ushort*)(w8 + 121634816);
    ushort* wab  = (ushort*)(w8 + 123731968);     // 2048x2048 bf16

    cast_kernel<<<8192, 256, 0, stream>>>(key, keyb);
    cast_kernel<<<8192, 256, 0, stream>>>(value, valb);
    cast_kernel<<<1024, 256, 0, stream>>>(wq, wqb);
    cast_kernel<<<1024, 256, 0, stream>>>(wk, wkb);
    cast_kernel<<<1024, 256, 0, stream>>>(wv, wvb);
    cast_kernel<<<4096, 256, 0, stream>>>(waoa, wab);
    ln_kernel<<<8192, 256, 0, stream>>>(query, ln_a, ln_b, xq);

    const float qscale = 0.08838834764831845f; // 1/sqrt(128)
    gemm2<<<512, 256, 0, stream>>>(xq + 1024, 2048, wqb, 1024, bq, Qb, 1024, 1024, 8, qscale, 0);
    gemm2<<<512, 256, 0, stream>>>(keyb, 1024, wkb, 1024, bk, Kb, 1024, 1024, 8, 1.f, 0);
    gemm2<<<512, 256, 0, stream>>>(valb, 1024, wvb, 1024, bv, Vt, 0, 1024, 8, 1.f, 1);

    attn_kernel<<<512, 512, 0, stream>>>(Qb, Kb, Vt, mask, xq);

    gemm2<<<1024, 256, 0, stream>>>(xq, 2048, wab, 2048, baoa, zb, 2048, 2048, 16, 1.f, 0);
    glu_kernel<<<8192, 256, 0, stream>>>(zb, out);
}

// Round 5
// 266.936 us; speedup vs baseline: 2.4526x; 1.0203x over previous
//
#include <hip/hip_runtime.h>

typedef __attribute__((ext_vector_type(8))) __bf16 bf16x8;
typedef __attribute__((ext_vector_type(4))) float f32x4;

__device__ __forceinline__ ushort f2b(float f) {
    uint u = __builtin_bit_cast(uint, f);
    u += 0x7fffu + ((u >> 16) & 1u);
    return (ushort)(u >> 16);
}
__device__ __forceinline__ float b2f(ushort h) {
    uint u = ((uint)h) << 16;
    return __builtin_bit_cast(float, u);
}

// ---------------- cast f32 -> bf16 (vec4) ----------------
__global__ __launch_bounds__(256) void cast_kernel(const float* __restrict__ src,
                                                   ushort* __restrict__ dst) {
    size_t i = ((size_t)blockIdx.x * 256 + threadIdx.x) * 4;
    float4 v = *(const float4*)(src + i);
    ushort4 o;
    o.x = f2b(v.x); o.y = f2b(v.y); o.z = f2b(v.z); o.w = f2b(v.w);
    *(ushort4*)(dst + i) = o;
}

// ---------------- LayerNorm(query) -> bf16 into xq[:,1024:2048] ----------------
__global__ __launch_bounds__(256) void ln_kernel(const float* __restrict__ x,
                                                 const float* __restrict__ ga,
                                                 const float* __restrict__ be,
                                                 ushort* __restrict__ xq) {
    const int row = blockIdx.x, tid = threadIdx.x;
    __shared__ float red[4];
    float4 v = ((const float4*)(x + (size_t)row * 1024))[tid];
    float sm = v.x + v.y + v.z + v.w;
    for (int off = 32; off; off >>= 1) sm += __shfl_xor(sm, off);
    if ((tid & 63) == 0) red[tid >> 6] = sm;
    __syncthreads();
    float mean = (red[0] + red[1] + red[2] + red[3]) * (1.f / 1024.f);
    __syncthreads();
    float dx = v.x - mean, dy = v.y - mean, dz = v.z - mean, dw = v.w - mean;
    float s2 = dx * dx + dy * dy + dz * dz + dw * dw;
    for (int off = 32; off; off >>= 1) s2 += __shfl_xor(s2, off);
    if ((tid & 63) == 0) red[tid >> 6] = s2;
    __syncthreads();
    float var = (red[0] + red[1] + red[2] + red[3]) * (1.f / 1023.f);
    float inv = 1.f / (sqrtf(var) + 1e-6f);
    float4 g = ((const float4*)ga)[tid];
    float4 bb = ((const float4*)be)[tid];
    ushort4 o;
    o.x = f2b(g.x * dx * inv + bb.x);
    o.y = f2b(g.y * dy * inv + bb.y);
    o.z = f2b(g.z * dz * inv + bb.z);
    o.w = f2b(g.w * dw * inv + bb.w);
    *(ushort4*)&xq[(size_t)row * 2048 + 1024 + tid * 4] = o;
}

// ---------------- GEMM v2: 128x128 tile, BK=64, T2 swizzle, 2-phase dbuf ----------------
__global__ __launch_bounds__(256) void gemm2(const ushort* __restrict__ A, int lda,
                                             const ushort* __restrict__ B, int ldb,
                                             const float* __restrict__ bias,
                                             ushort* __restrict__ C, int ldc,
                                             int K, int NB, float scale, int mode) {
    __shared__ ushort As[2][8192];
    __shared__ ushort Bs[2][8192];
    const int tid = threadIdx.x;
    const int w = tid >> 6, l = tid & 63;
    const int wr = w >> 1, wc = w & 1;
    const int r16 = l & 15, g4 = l >> 4;

    const int bid = blockIdx.x;
    const int cpx = gridDim.x >> 3;
    const int swz = (bid & 7) * cpx + (bid >> 3);
    const int m0 = (swz / NB) * 128;
    const int n0 = (swz % NB) * 128;

    const int srow = l >> 3;
    const int scol = ((l & 7) ^ srow) * 8;
    const ushort* Asrc = A + (size_t)(m0 + w * 8 + srow) * lda + scol;
    const ushort* Bsrc = B + (size_t)(n0 + w * 8 + srow) * ldb + scol;

    f32x4 acc[4][4];
#pragma unroll
    for (int i = 0; i < 4; i++)
#pragma unroll
        for (int j = 0; j < 4; j++) acc[i][j] = (f32x4){0.f, 0.f, 0.f, 0.f};

    auto STAGE = [&](int sel, int kt) {
#pragma unroll
        for (int it = 0; it < 4; it++) {
            __builtin_amdgcn_global_load_lds(
                (const __attribute__((address_space(1))) void*)(Asrc + (size_t)(it * 32) * lda + kt * 64),
                (__attribute__((address_space(3))) void*)(&As[sel][(it * 4 + w) * 512]), 16, 0, 0);
            __builtin_amdgcn_global_load_lds(
                (const __attribute__((address_space(1))) void*)(Bsrc + (size_t)(it * 32) * ldb + kt * 64),
                (__attribute__((address_space(3))) void*)(&Bs[sel][(it * 4 + w) * 512]), 16, 0, 0);
        }
    };

    const int swzr = (g4 ^ (r16 & 7)) << 4;

    auto COMPUTE = [&](int sel, int kt, bool stage_next) {
        if (stage_next) STAGE(sel ^ 1, kt + 1);
        const char* Ab = (const char*)&As[sel][0];
        const char* Bb = (const char*)&Bs[sel][0];
        bf16x8 af[4][2], bfv[4][2];
#pragma unroll
        for (int mi = 0; mi < 4; mi++) {
            int ba = (wr * 64 + mi * 16 + r16) * 128 + swzr;
            af[mi][0] = *(const bf16x8*)(Ab + ba);
            af[mi][1] = *(const bf16x8*)(Ab + (ba ^ 64));
        }
#pragma unroll
        for (int ni = 0; ni < 4; ni++) {
            int bb = (wc * 64 + ni * 16 + r16) * 128 + swzr;
            bfv[ni][0] = *(const bf16x8*)(Bb + bb);
            bfv[ni][1] = *(const bf16x8*)(Bb + (bb ^ 64));
        }
        __builtin_amdgcn_s_setprio(1);
#pragma unroll
        for (int ks = 0; ks < 2; ks++)
#pragma unroll
            for (int mi = 0; mi < 4; mi++)
#pragma unroll
                for (int ni = 0; ni < 4; ni++)
                    acc[mi][ni] = __builtin_amdgcn_mfma_f32_16x16x32_bf16(af[mi][ks], bfv[ni][ks], acc[mi][ni], 0, 0, 0);
        __builtin_amdgcn_s_setprio(0);
        asm volatile("s_waitcnt vmcnt(0)" ::: "memory");
        __syncthreads();
    };

    STAGE(0, 0);
    asm volatile("s_waitcnt vmcnt(0)" ::: "memory");
    __syncthreads();
    const int NT = K >> 6;
    for (int kt = 0; kt < NT; kt += 2) {
        COMPUTE(0, kt, true);
        COMPUTE(1, kt + 1, kt + 2 < NT);
    }

    const int row0 = m0 + wr * 64;
    const int col0 = n0 + wc * 64;
    if (mode == 0) {
#pragma unroll
        for (int ni = 0; ni < 4; ni++) {
            int n = col0 + ni * 16 + r16;
            float bs = bias[n];
#pragma unroll
            for (int mi = 0; mi < 4; mi++) {
                int mr = row0 + mi * 16 + g4 * 4;
#pragma unroll
                for (int r = 0; r < 4; r++) {
                    C[(size_t)(mr + r) * ldc + n] = f2b((acc[mi][ni][r] + bs) * scale);
                }
            }
        }
    } else {
#pragma unroll
        for (int ni = 0; ni < 4; ni++) {
            int n = col0 + ni * 16 + r16;
            float bs = bias[n];
            int h = n >> 7, d = n & 127;
#pragma unroll
            for (int mi = 0; mi < 4; mi++) {
                int m = row0 + mi * 16 + g4 * 4;
                int b_ = m >> 10, s_ = m & 1023;
                ushort4 o;
                o.x = f2b((acc[mi][ni][0] + bs) * scale);
                o.y = f2b((acc[mi][ni][1] + bs) * scale);
                o.z = f2b((acc[mi][ni][2] + bs) * scale);
                o.w = f2b((acc[mi][ni][3] + bs) * scale);
                *(ushort4*)&C[((size_t)(b_ * 8 + h) * 128 + d) * 1024 + s_] = o;
            }
        }
    }
}

// ---------------- GEMM v3: 256x256 tile, BK=64, 8-phase-style counted-vmcnt pipeline ----------------
// C[m][n] = sum_k A[m][k]*B[n][k] + bias[n], bf16 out. 8 waves: wr=wid>>2 (M), wcn=wid&3 (N).
// Wave rows INTERLEAVED: R = wr*16 + 32*a (a=0..7) -> a<4 in A-low half, a>=4 in A-high.
// Wave cols: Nc = wcn*16 + 64*b (b=0..3) -> b<2 B-low, b>=2 B-high.
// Per K-tile: 4 phases, quadrants [(aL,bL),(aH,bL),(aH,bH),(aL,bH)];
// staging order of tile t+1: [AL,BL,AH,BH], one half-tile (2 gload_lds) per phase.
// Uniform s_waitcnt vmcnt(4) before the post-MFMA barrier retires exactly the
// half-tile the NEXT phase consumes (every half-tile gets >=3 phases in flight).
// Raw s_barrier (NOT __syncthreads) so vmcnt stays counted across barriers.
__global__ __launch_bounds__(512, 2) void gemm3(const ushort* __restrict__ A, int lda,
                                                const ushort* __restrict__ B, int ldb,
                                                const float* __restrict__ bias,
                                                ushort* __restrict__ C, int ldc,
                                                int K, int NB) {
    __shared__ ushort lds[2][32768];   // per buf: A 256x64 (32KB) | B 256x64 (32KB)

    const int tid = threadIdx.x;
    const int w = tid >> 6, l = tid & 63;
    const int wr = w >> 2, wcn = w & 3;
    const int r16 = l & 15, g4 = l >> 4;

    const int bid = blockIdx.x;
    const int cpx = gridDim.x >> 3;
    const int swz = (bid & 7) * cpx + (bid >> 3);
    const int m0 = (swz / NB) * 256;
    const int n0 = (swz % NB) * 256;

    // staging source (pre-swizzled global column so linear LDS dest + XOR read works)
    const int srow8 = l >> 3;                    // 0..7
    const int sxor8 = ((l & 7) ^ srow8) * 8;     // element offset of this lane's 16B chunk
    const ushort* As0 = A + (size_t)(m0 + w * 8 + srow8) * lda + sxor8;
    const ushort* Bs0 = B + (size_t)(n0 + w * 8 + srow8) * ldb + sxor8;

    f32x4 acc[8][4];
#pragma unroll
    for (int i = 0; i < 8; i++)
#pragma unroll
        for (int j = 0; j < 4; j++) acc[i][j] = (f32x4){0.f, 0.f, 0.f, 0.f};

    const int sw16 = (r16 & 7) << 4;
    char* ldsb = (char*)&lds[0][0];

    // stage half-tile HS (0=AL,1=BL,2=AH,3=BH) of K-tile kt into buffer sel
#define STAGE_H(sel_, HS_, kt_)                                                            \
    do {                                                                                   \
        const int mat_ = (HS_)&1, half_ = (HS_) >> 1;                                      \
        const ushort* sb_ = mat_ ? Bs0 : As0;                                              \
        const int ld_ = mat_ ? ldb : lda;                                                  \
        _Pragma("unroll") for (int li_ = 0; li_ < 2; li_++) {                              \
            const ushort* src_ = sb_ + (size_t)(half_ * 128 + li_ * 64) * ld_ + (kt_)*64;  \
            int dst_ = (sel_)*65536 + mat_ * 32768 + half_ * 16384 + li_ * 8192 + w * 1024;\
            __builtin_amdgcn_global_load_lds(                                              \
                (const __attribute__((address_space(1))) void*)src_,                       \
                (__attribute__((address_space(3))) void*)(ldsb + dst_), 16, 0, 0);         \
        }                                                                                  \
    } while (0)

    // fragment reads from LDS (sel in bytes base), a in 0..7 / b in 0..3, ks in 0..1
#define RD_A(sel_, a_, ks_)                                                                  \
    (*(const bf16x8*)(ldsb + (sel_)*65536 + ((a_) >> 2) * 16384 +                            \
                      (wr * 16 + 32 * ((a_)&3) + r16) * 128 + (((ks_)*64 + g4 * 16) ^ sw16)))
#define RD_B(sel_, b_, ks_)                                                                  \
    (*(const bf16x8*)(ldsb + (sel_)*65536 + 32768 + ((b_) >> 1) * 16384 +                    \
                      (wcn * 16 + 64 * ((b_)&1) + r16) * 128 + (((ks_)*64 + g4 * 16) ^ sw16)))

    const int NT = K >> 6;

    // prologue: full tile 0 into buf 0
    STAGE_H(0, 0, 0); STAGE_H(0, 1, 0); STAGE_H(0, 2, 0); STAGE_H(0, 3, 0);
    asm volatile("s_waitcnt vmcnt(0)" ::: "memory");
    __builtin_amdgcn_s_barrier();

    bf16x8 afr[4][2], bfr[2][2];

#define PHASE(sel_, t_, A0_, B0_, RDA_, RDB_, HS_)                                          \
    do {                                                                                    \
        if (RDA_) {                                                                         \
            _Pragma("unroll") for (int ai_ = 0; ai_ < 4; ai_++)                             \
                _Pragma("unroll") for (int ks_ = 0; ks_ < 2; ks_++)                         \
                    afr[ai_][ks_] = RD_A(sel_, (A0_) + ai_, ks_);                           \
        }                                                                                   \
        if (RDB_) {                                                                         \
            _Pragma("unroll") for (int bi_ = 0; bi_ < 2; bi_++)                             \
                _Pragma("unroll") for (int ks_ = 0; ks_ < 2; ks_++)                         \
                    bfr[bi_][ks_] = RD_B(sel_, (B0_) + bi_, ks_);                           \
        }                                                                                   \
        if ((t_) + 1 < NT) STAGE_H((sel_) ^ 1, HS_, (t_) + 1);                              \
        __builtin_amdgcn_s_barrier();                                                       \
        __builtin_amdgcn_s_setprio(1);                                                      \
        _Pragma("unroll") for (int ks_ = 0; ks_ < 2; ks_++)                                 \
            _Pragma("unroll") for (int ai_ = 0; ai_ < 4; ai_++)                             \
                _Pragma("unroll") for (int bi_ = 0; bi_ < 2; bi_++)                         \
                    acc[(A0_) + ai_][(B0_) + bi_] = __builtin_amdgcn_mfma_f32_16x16x32_bf16(\
                        afr[ai_][ks_], bfr[bi_][ks_], acc[(A0_) + ai_][(B0_) + bi_], 0, 0, 0);\
        __builtin_amdgcn_s_setprio(0);                                                      \
        asm volatile("s_waitcnt vmcnt(4)" ::: "memory");                                    \
        __builtin_amdgcn_s_barrier();                                                       \
    } while (0)

    for (int t = 0; t < NT; ++t) {
        const int sel = t & 1;
        PHASE(sel, t, 0, 0, 1, 1, 0);   // (aL,bL): read A-low + B-low;  stage AL(t+1)
        PHASE(sel, t, 4, 0, 1, 0, 1);   // (aH,bL): read A-high;         stage BL(t+1)
        PHASE(sel, t, 4, 2, 0, 1, 2);   // (aH,bH): read B-high;         stage AH(t+1)
        PHASE(sel, t, 0, 2, 1, 0, 3);   // (aL,bH): read A-low;          stage BH(t+1)
    }
#undef PHASE
#undef RD_A
#undef RD_B
#undef STAGE_H

    // epilogue: R = m0 + wr*16 + 32a + g4*4 + r ; Nc = n0 + wcn*16 + 64b + r16
#pragma unroll
    for (int b_ = 0; b_ < 4; b_++) {
        int n = n0 + wcn * 16 + 64 * b_ + r16;
        float bs = bias[n];
#pragma unroll
        for (int a_ = 0; a_ < 8; a_++) {
            int mr = m0 + wr * 16 + 32 * a_ + g4 * 4;
#pragma unroll
            for (int r = 0; r < 4; r++) {
                C[(size_t)(mr + r) * ldc + n] = f2b(acc[a_][b_][r] + bs);
            }
        }
    }
}

// ---------------- flash attention v3: swapped-operand (S^T / x^T), lane-local softmax ----------------
__global__ __launch_bounds__(512, 4) void attn_kernel(const ushort* __restrict__ Q,
                                                      const ushort* __restrict__ Kt,
                                                      const ushort* __restrict__ Vt,
                                                      const int* __restrict__ mask,
                                                      ushort* __restrict__ xq) {
    __shared__ ushort Ks[2][8192];   // [64 kv][128 d], row=256B, XOR swz ((row&7)<<4 bytes)
    __shared__ ushort Vs[2][8192];   // [128 d][64 s],  row=128B, XOR swz ((d&7)<<4 bytes)
    __shared__ ushort Pl[8][1024];   // per-wave [16 q][64 kv], 128B rows, XOR swz ((q&7)<<4 bytes)

    const int tid = threadIdx.x;
    const int l = tid & 63, wid = tid >> 6;
    const int r16 = l & 15, g4 = l >> 4;
    const int id = blockIdx.x;
    const int bh = ((id >> 6) << 3) | (id & 7);   // same-bh blocks differ by 8 -> same XCD
    const int qb = (id >> 3) & 7;
    const int b = bh >> 3, h = bh & 7;
    const int q0 = qb * 128 + wid * 16;

    bf16x8 qf[4];
    const ushort* Qrow = Q + (size_t)(b * 1024 + q0 + r16) * 1024 + h * 128 + g4 * 8;
#pragma unroll
    for (int kf = 0; kf < 4; kf++) qf[kf] = *(const bf16x8*)(Qrow + kf * 32);

    const ushort* Kg = Kt + ((size_t)b * 1024) * 1024 + h * 128; // + s*1024 + d
    const ushort* Vg = Vt + (size_t)(b * 8 + h) * 128 * 1024;    // + d*1024 + s
    const int* mptr = mask + b * 1024;
    int mv = mptr[l];

    f32x4 xacc[8];
#pragma unroll
    for (int i = 0; i < 8; i++) xacc[i] = (f32x4){0.f, 0.f, 0.f, 0.f};
    float mrow = -INFINITY, lrow = 0.f;

    char* Pme = (char*)&Pl[wid][0];
    const int pswz = (r16 & 7) << 4;

    auto STAGE = [&](int sel, int t) {
        const int kv0 = t * 64;
#pragma unroll
        for (int it = 0; it < 2; ++it) {
            int ob = it * 8192 + wid * 1024;
            int o = ob + l * 16;
            int row = o >> 8;
            int sc = (o & 255) ^ ((row & 7) << 4);
            const ushort* src = Kg + (size_t)(kv0 + row) * 1024 + (sc >> 1);
            __builtin_amdgcn_global_load_lds((const __attribute__((address_space(1))) void*)src,
                (__attribute__((address_space(3))) void*)((char*)&Ks[sel][0] + ob), 16, 0, 0);
        }
#pragma unroll
        for (int it = 0; it < 2; ++it) {
            int ob = it * 8192 + wid * 1024;
            int o = ob + l * 16;
            int d = o >> 7;
            int sc = (o & 127) ^ ((d & 7) << 4);
            const ushort* src = Vg + (size_t)d * 1024 + kv0 + (sc >> 1);
            __builtin_amdgcn_global_load_lds((const __attribute__((address_space(1))) void*)src,
                (__attribute__((address_space(3))) void*)((char*)&Vs[sel][0] + ob), 16, 0, 0);
        }
    };

    STAGE(0, 0);
    int cur = 0;

    for (int t = 0; t < 16; ++t) {
        int mvn = (t < 15) ? mptr[(t + 1) * 64 + l] : 0;
        unsigned long long wt = __ballot(mv != 0);

        asm volatile("s_waitcnt vmcnt(0)" ::: "memory");
        __syncthreads();
        if (t < 15) STAGE(cur ^ 1, t + 1);

        const char* Kb_ = (const char*)&Ks[cur][0];
        const char* Vb_ = (const char*)&Vs[cur][0];

        f32x4 s[4];
#pragma unroll
        for (int cg = 0; cg < 4; cg++) {
            s[cg] = (f32x4){0.f, 0.f, 0.f, 0.f};
            const int rowk = cg * 16 + r16;
            const char* kr = Kb_ + rowk * 256;
            const int sw = (rowk & 7) << 4;
#pragma unroll
            for (int kf = 0; kf < 4; kf++) {
                bf16x8 kfr = *(const bf16x8*)(kr + ((kf * 64 + g4 * 16) ^ sw));
                s[cg] = __builtin_amdgcn_mfma_f32_16x16x32_bf16(kfr, qf[kf], s[cg], 0, 0, 0);
            }
            uint nib = (uint)(wt >> (cg * 16 + g4 * 4)) & 15u;
#pragma unroll
            for (int r = 0; r < 4; r++)
                if (!((nib >> r) & 1u)) s[cg][r] = -1e9f;
        }

        float pmax = -INFINITY;
#pragma unroll
        for (int cg = 0; cg < 4; cg++)
#pragma unroll
            for (int r = 0; r < 4; r++) pmax = fmaxf(pmax, s[cg][r]);
        pmax = fmaxf(pmax, __shfl_xor(pmax, 16));
        pmax = fmaxf(pmax, __shfl_xor(pmax, 32));
        float mn = fmaxf(mrow, pmax);
        float scl = __expf(mrow - mn);
        mrow = mn;

        float rsum = 0.f;
#pragma unroll
        for (int cg = 0; cg < 4; cg++)
#pragma unroll
            for (int r = 0; r < 4; r++) {
                float p = __expf(s[cg][r] - mn);
                s[cg][r] = p;
                rsum += p;
            }
        rsum += __shfl_xor(rsum, 16);
        rsum += __shfl_xor(rsum, 32);
        lrow = lrow * scl + rsum;

#pragma unroll
        for (int cg = 0; cg < 4; cg++) {
            uint lo = ((uint)f2b(s[cg][1]) << 16) | f2b(s[cg][0]);
            uint hi = ((uint)f2b(s[cg][3]) << 16) | f2b(s[cg][2]);
            uint2 pk; pk.x = lo; pk.y = hi;
            *(uint2*)(Pme + r16 * 128 + ((cg * 32 + g4 * 8) ^ pswz)) = pk;
        }

#pragma unroll
        for (int cg2 = 0; cg2 < 8; cg2++)
#pragma unroll
            for (int r = 0; r < 4; r++) xacc[cg2][r] *= scl;

#pragma unroll
        for (int ks = 0; ks < 2; ks++) {
            bf16x8 pfr = *(const bf16x8*)(Pme + r16 * 128 + ((g4 * 16 + ks * 64) ^ pswz));
#pragma unroll
            for (int cg2 = 0; cg2 < 8; cg2++) {
                const int d = cg2 * 16 + r16;
                bf16x8 vfr = *(const bf16x8*)(Vb_ + d * 128 + ((ks * 64 + g4 * 16) ^ ((d & 7) << 4)));
                xacc[cg2] = __builtin_amdgcn_mfma_f32_16x16x32_bf16(vfr, pfr, xacc[cg2], 0, 0, 0);
            }
        }
        mv = mvn;
        cur ^= 1;
    }

    const float inv = 1.f / lrow;
    const size_t orow = (size_t)(b * 1024 + q0 + r16) * 2048 + h * 128;
#pragma unroll
    for (int cg2 = 0; cg2 < 8; cg2++) {
#pragma unroll
        for (int r = 0; r < 4; r++) {
            xq[orow + cg2 * 16 + g4 * 4 + r] = f2b(xacc[cg2][r] * inv);
        }
    }
}

// ---------------- GLU: out = a * sigmoid(g) ----------------
__global__ __launch_bounds__(256) void glu_kernel(const ushort* __restrict__ z,
                                                  float* __restrict__ out) {
    size_t i = (size_t)blockIdx.x * 1024 + (size_t)threadIdx.x * 4;
    size_t row = i >> 10;
    int c = (int)(i & 1023);
    ushort4 av = *(const ushort4*)&z[row * 2048 + c];
    ushort4 gv = *(const ushort4*)&z[row * 2048 + 1024 + c];
    float4 o;
    o.x = b2f(av.x) * (1.f / (1.f + __expf(-b2f(gv.x))));
    o.y = b2f(av.y) * (1.f / (1.f + __expf(-b2f(gv.y))));
    o.z = b2f(av.z) * (1.f / (1.f + __expf(-b2f(gv.z))));
    o.w = b2f(av.w) * (1.f / (1.f + __expf(-b2f(gv.w))));
    *(float4*)&out[i] = o;
}

extern "C" void kernel_launch(void* const* d_in, const int* in_sizes, int n_in,
                              void* d_out, int out_size, void* d_ws, size_t ws_size,
                              hipStream_t stream) {
    const float* query = (const float*)d_in[0];
    const float* value = (const float*)d_in[1];
    const float* key   = (const float*)d_in[2];
    const int*   mask  = (const int*)d_in[3];
    const float* ln_a  = (const float*)d_in[4];
    const float* ln_b  = (const float*)d_in[5];
    const float* wq    = (const float*)d_in[6];
    const float* bq    = (const float*)d_in[7];
    const float* wk    = (const float*)d_in[8];
    const float* bk    = (const float*)d_in[9];
    const float* wv    = (const float*)d_in[10];
    const float* bv    = (const float*)d_in[11];
    const float* waoa  = (const float*)d_in[12];
    const float* baoa  = (const float*)d_in[13];
    float* out = (float*)d_out;

    char* w8 = (char*)d_ws;
    ushort* xq   = (ushort*)(w8);                 // 8192x2048 bf16 ([x | q_ln])
    ushort* Qb   = (ushort*)(w8 + 33554432);      // 8192x1024 bf16
    ushort* Kb   = (ushort*)(w8 + 50331648);      // 8192x1024 bf16
    ushort* Vt   = (ushort*)(w8 + 67108864);      // (B,H,128,S) bf16
    ushort* keyb = (ushort*)(w8 + 83886080);      // 8192x1024 bf16
    ushort* valb = (ushort*)(w8 + 100663296);     // 8192x1024 bf16
    ushort* zb   = (ushort*)(w8 + 83886080);      // aliases keyb/valb (dead by AOA time)
    ushort* wqb  = (ushort*)(w8 + 117440512);
    ushort* wkb  = (ushort*)(w8 + 119537664);
    ushort* wvb  = (ushort*)(w8 + 121634816);
    ushort* wab  = (ushort*)(w8 + 123731968);     // 2048x2048 bf16

    cast_kernel<<<8192, 256, 0, stream>>>(key, keyb);
    cast_kernel<<<8192, 256, 0, stream>>>(value, valb);
    cast_kernel<<<1024, 256, 0, stream>>>(wq, wqb);
    cast_kernel<<<1024, 256, 0, stream>>>(wk, wkb);
    cast_kernel<<<1024, 256, 0, stream>>>(wv, wvb);
    cast_kernel<<<4096, 256, 0, stream>>>(waoa, wab);
    ln_kernel<<<8192, 256, 0, stream>>>(query, ln_a, ln_b, xq);

    const float qscale = 0.08838834764831845f; // 1/sqrt(128)
    gemm2<<<512, 256, 0, stream>>>(xq + 1024, 2048, wqb, 1024, bq, Qb, 1024, 1024, 8, qscale, 0);
    gemm2<<<512, 256, 0, stream>>>(keyb, 1024, wkb, 1024, bk, Kb, 1024, 1024, 8, 1.f, 0);
    gemm2<<<512, 256, 0, stream>>>(valb, 1024, wvb, 1024, bv, Vt, 0, 1024, 8, 1.f, 1);

    attn_kernel<<<512, 512, 0, stream>>>(Qb, Kb, Vt, mask, xq);

    // AOA: M=8192, N=2048, K=2048 -> 32x8 = 256 blocks (1/CU), 8-phase pipeline
    gemm3<<<256, 512, 0, stream>>>(xq, 2048, wab, 2048, baoa, zb, 2048, 2048, 8);
    glu_kernel<<<8192, 256, 0, stream>>>(zb, out);
}

// Round 6
// 242.596 us; speedup vs baseline: 2.6987x; 1.1003x over previous
//
#include <hip/hip_runtime.h>

typedef __attribute__((ext_vector_type(8))) __bf16 bf16x8;
typedef __attribute__((ext_vector_type(4))) float f32x4;

__device__ __forceinline__ ushort f2b(float f) {
    uint u = __builtin_bit_cast(uint, f);
    u += 0x7fffu + ((u >> 16) & 1u);
    return (ushort)(u >> 16);
}
__device__ __forceinline__ float b2f(ushort h) {
    uint u = ((uint)h) << 16;
    return __builtin_bit_cast(float, u);
}

// ---------------- cast f32 -> bf16 (vec4) ----------------
__global__ __launch_bounds__(256) void cast_kernel(const float* __restrict__ src,
                                                   ushort* __restrict__ dst) {
    size_t i = ((size_t)blockIdx.x * 256 + threadIdx.x) * 4;
    float4 v = *(const float4*)(src + i);
    ushort4 o;
    o.x = f2b(v.x); o.y = f2b(v.y); o.z = f2b(v.z); o.w = f2b(v.w);
    *(ushort4*)(dst + i) = o;
}

// ---------------- cast + ROW-PERMUTE w_aoa so (a_j, g_j) output columns pair up ----------------
// dst row n' = src row q(n') = ((n'&63) | ((n'>>7)<<6)) + 1024*((n'>>6)&1)
__global__ __launch_bounds__(256) void cast_permute_aoa(const float* __restrict__ src,
                                                        ushort* __restrict__ dst) {
    int n1 = blockIdx.x >> 1;
    int c = (blockIdx.x & 1) * 1024 + threadIdx.x * 4;
    int q = ((n1 & 63) | ((n1 >> 7) << 6)) + ((n1 >> 6) & 1) * 1024;
    float4 v = *(const float4*)(src + (size_t)q * 2048 + c);
    ushort4 o;
    o.x = f2b(v.x); o.y = f2b(v.y); o.z = f2b(v.z); o.w = f2b(v.w);
    *(ushort4*)(dst + (size_t)n1 * 2048 + c) = o;
}

// ---------------- LayerNorm(query) -> bf16 into xq[:,1024:2048] ----------------
__global__ __launch_bounds__(256) void ln_kernel(const float* __restrict__ x,
                                                 const float* __restrict__ ga,
                                                 const float* __restrict__ be,
                                                 ushort* __restrict__ xq) {
    const int row = blockIdx.x, tid = threadIdx.x;
    __shared__ float red[4];
    float4 v = ((const float4*)(x + (size_t)row * 1024))[tid];
    float sm = v.x + v.y + v.z + v.w;
    for (int off = 32; off; off >>= 1) sm += __shfl_xor(sm, off);
    if ((tid & 63) == 0) red[tid >> 6] = sm;
    __syncthreads();
    float mean = (red[0] + red[1] + red[2] + red[3]) * (1.f / 1024.f);
    __syncthreads();
    float dx = v.x - mean, dy = v.y - mean, dz = v.z - mean, dw = v.w - mean;
    float s2 = dx * dx + dy * dy + dz * dz + dw * dw;
    for (int off = 32; off; off >>= 1) s2 += __shfl_xor(s2, off);
    if ((tid & 63) == 0) red[tid >> 6] = s2;
    __syncthreads();
    float var = (red[0] + red[1] + red[2] + red[3]) * (1.f / 1023.f);
    float inv = 1.f / (sqrtf(var) + 1e-6f);
    float4 g = ((const float4*)ga)[tid];
    float4 bb = ((const float4*)be)[tid];
    ushort4 o;
    o.x = f2b(g.x * dx * inv + bb.x);
    o.y = f2b(g.y * dy * inv + bb.y);
    o.z = f2b(g.z * dz * inv + bb.z);
    o.w = f2b(g.w * dw * inv + bb.w);
    *(ushort4*)&xq[(size_t)row * 2048 + 1024 + tid * 4] = o;
}

// ---------------- GEMM v2: 128x128 tile, BK=64, T2 swizzle, 2-phase dbuf ----------------
__global__ __launch_bounds__(256) void gemm2(const ushort* __restrict__ A, int lda,
                                             const ushort* __restrict__ B, int ldb,
                                             const float* __restrict__ bias,
                                             ushort* __restrict__ C, int ldc,
                                             int K, int NB, float scale, int mode) {
    __shared__ ushort As[2][8192];
    __shared__ ushort Bs[2][8192];
    const int tid = threadIdx.x;
    const int w = tid >> 6, l = tid & 63;
    const int wr = w >> 1, wc = w & 1;
    const int r16 = l & 15, g4 = l >> 4;

    const int bid = blockIdx.x;
    const int cpx = gridDim.x >> 3;
    const int swz = (bid & 7) * cpx + (bid >> 3);
    const int m0 = (swz / NB) * 128;
    const int n0 = (swz % NB) * 128;

    const int srow = l >> 3;
    const int scol = ((l & 7) ^ srow) * 8;
    const ushort* Asrc = A + (size_t)(m0 + w * 8 + srow) * lda + scol;
    const ushort* Bsrc = B + (size_t)(n0 + w * 8 + srow) * ldb + scol;

    f32x4 acc[4][4];
#pragma unroll
    for (int i = 0; i < 4; i++)
#pragma unroll
        for (int j = 0; j < 4; j++) acc[i][j] = (f32x4){0.f, 0.f, 0.f, 0.f};

    auto STAGE = [&](int sel, int kt) {
#pragma unroll
        for (int it = 0; it < 4; it++) {
            __builtin_amdgcn_global_load_lds(
                (const __attribute__((address_space(1))) void*)(Asrc + (size_t)(it * 32) * lda + kt * 64),
                (__attribute__((address_space(3))) void*)(&As[sel][(it * 4 + w) * 512]), 16, 0, 0);
            __builtin_amdgcn_global_load_lds(
                (const __attribute__((address_space(1))) void*)(Bsrc + (size_t)(it * 32) * ldb + kt * 64),
                (__attribute__((address_space(3))) void*)(&Bs[sel][(it * 4 + w) * 512]), 16, 0, 0);
        }
    };

    const int swzr = (g4 ^ (r16 & 7)) << 4;

    auto COMPUTE = [&](int sel, int kt, bool stage_next) {
        if (stage_next) STAGE(sel ^ 1, kt + 1);
        const char* Ab = (const char*)&As[sel][0];
        const char* Bb = (const char*)&Bs[sel][0];
        bf16x8 af[4][2], bfv[4][2];
#pragma unroll
        for (int mi = 0; mi < 4; mi++) {
            int ba = (wr * 64 + mi * 16 + r16) * 128 + swzr;
            af[mi][0] = *(const bf16x8*)(Ab + ba);
            af[mi][1] = *(const bf16x8*)(Ab + (ba ^ 64));
        }
#pragma unroll
        for (int ni = 0; ni < 4; ni++) {
            int bb = (wc * 64 + ni * 16 + r16) * 128 + swzr;
            bfv[ni][0] = *(const bf16x8*)(Bb + bb);
            bfv[ni][1] = *(const bf16x8*)(Bb + (bb ^ 64));
        }
        __builtin_amdgcn_s_setprio(1);
#pragma unroll
        for (int ks = 0; ks < 2; ks++)
#pragma unroll
            for (int mi = 0; mi < 4; mi++)
#pragma unroll
                for (int ni = 0; ni < 4; ni++)
                    acc[mi][ni] = __builtin_amdgcn_mfma_f32_16x16x32_bf16(af[mi][ks], bfv[ni][ks], acc[mi][ni], 0, 0, 0);
        __builtin_amdgcn_s_setprio(0);
        asm volatile("s_waitcnt vmcnt(0)" ::: "memory");
        __syncthreads();
    };

    STAGE(0, 0);
    asm volatile("s_waitcnt vmcnt(0)" ::: "memory");
    __syncthreads();
    const int NT = K >> 6;
    for (int kt = 0; kt < NT; kt += 2) {
        COMPUTE(0, kt, true);
        COMPUTE(1, kt + 1, kt + 2 < NT);
    }

    const int row0 = m0 + wr * 64;
    const int col0 = n0 + wc * 64;
    if (mode == 0) {
#pragma unroll
        for (int ni = 0; ni < 4; ni++) {
            int n = col0 + ni * 16 + r16;
            float bs = bias[n];
#pragma unroll
            for (int mi = 0; mi < 4; mi++) {
                int mr = row0 + mi * 16 + g4 * 4;
#pragma unroll
                for (int r = 0; r < 4; r++) {
                    C[(size_t)(mr + r) * ldc + n] = f2b((acc[mi][ni][r] + bs) * scale);
                }
            }
        }
    } else {
#pragma unroll
        for (int ni = 0; ni < 4; ni++) {
            int n = col0 + ni * 16 + r16;
            float bs = bias[n];
            int h = n >> 7, d = n & 127;
#pragma unroll
            for (int mi = 0; mi < 4; mi++) {
                int m = row0 + mi * 16 + g4 * 4;
                int b_ = m >> 10, s_ = m & 1023;
                ushort4 o;
                o.x = f2b((acc[mi][ni][0] + bs) * scale);
                o.y = f2b((acc[mi][ni][1] + bs) * scale);
                o.z = f2b((acc[mi][ni][2] + bs) * scale);
                o.w = f2b((acc[mi][ni][3] + bs) * scale);
                *(ushort4*)&C[((size_t)(b_ * 8 + h) * 128 + d) * 1024 + s_] = o;
            }
        }
    }
}

// ---------------- GEMM v3: 256x256, BK=64, 4-phase counted-vmcnt, frag reuse, FUSED GLU ----------------
// Inputs: A (M x 2048 bf16), B = PERMUTED w_aoa (2048 x 2048 bf16), bias = raw b_aoa (f32, 2048).
// Output: out f32 (M x 1024), out[m][j] = a*sigmoid(g), pair j from acc cols (2bp, 2bp+1).
__global__ __launch_bounds__(512, 2) void gemm3(const ushort* __restrict__ A, int lda,
                                                const ushort* __restrict__ B, int ldb,
                                                const float* __restrict__ bias,
                                                float* __restrict__ out,
                                                int K, int NB) {
    __shared__ ushort lds[2][32768];   // per buf: A 256x64 (32KB) | B 256x64 (32KB)

    const int tid = threadIdx.x;
    const int w = tid >> 6, l = tid & 63;
    const int wr = w >> 2, wcn = w & 3;
    const int r16 = l & 15, g4 = l >> 4;

    const int bid = blockIdx.x;
    const int cpx = gridDim.x >> 3;
    const int swz = (bid & 7) * cpx + (bid >> 3);
    const int m0 = (swz / NB) * 256;
    const int n0 = (swz % NB) * 256;

    const int srow8 = l >> 3;
    const int sxor8 = ((l & 7) ^ srow8) * 8;
    const ushort* As0 = A + (size_t)(m0 + w * 8 + srow8) * lda + sxor8;
    const ushort* Bs0 = B + (size_t)(n0 + w * 8 + srow8) * ldb + sxor8;

    f32x4 acc[8][4];
#pragma unroll
    for (int i = 0; i < 8; i++)
#pragma unroll
        for (int j = 0; j < 4; j++) acc[i][j] = (f32x4){0.f, 0.f, 0.f, 0.f};

    const int sw16 = (r16 & 7) << 4;
    char* ldsb = (char*)&lds[0][0];

#define STAGE_H(sel_, HS_, kt_)                                                            \
    do {                                                                                   \
        const int mat_ = (HS_)&1, half_ = (HS_) >> 1;                                      \
        const ushort* sb_ = mat_ ? Bs0 : As0;                                              \
        const int ld_ = mat_ ? ldb : lda;                                                  \
        _Pragma("unroll") for (int li_ = 0; li_ < 2; li_++) {                              \
            const ushort* src_ = sb_ + (size_t)(half_ * 128 + li_ * 64) * ld_ + (kt_)*64;  \
            int dst_ = (sel_)*65536 + mat_ * 32768 + half_ * 16384 + li_ * 8192 + w * 1024;\
            __builtin_amdgcn_global_load_lds(                                              \
                (const __attribute__((address_space(1))) void*)src_,                       \
                (__attribute__((address_space(3))) void*)(ldsb + dst_), 16, 0, 0);         \
        }                                                                                  \
    } while (0)

    auto LDA4 = [&](bf16x8 (&dst)[4][2], int sel, int half) {
#pragma unroll
        for (int ai = 0; ai < 4; ai++)
#pragma unroll
            for (int ks = 0; ks < 2; ks++)
                dst[ai][ks] = *(const bf16x8*)(ldsb + sel * 65536 + half * 16384 +
                                               (wr * 16 + 32 * ai + r16) * 128 +
                                               ((ks * 64 + g4 * 16) ^ sw16));
    };
    auto LDB2 = [&](bf16x8 (&dst)[2][2], int sel, int half) {
#pragma unroll
        for (int bi = 0; bi < 2; bi++)
#pragma unroll
            for (int ks = 0; ks < 2; ks++)
                dst[bi][ks] = *(const bf16x8*)(ldsb + sel * 65536 + 32768 + half * 16384 +
                                               (wcn * 16 + 64 * bi + r16) * 128 +
                                               ((ks * 64 + g4 * 16) ^ sw16));
    };
    auto MM = [&](bf16x8 (&af)[4][2], bf16x8 (&bf)[2][2], int A0, int B0) {
        __builtin_amdgcn_s_setprio(1);
#pragma unroll
        for (int ks = 0; ks < 2; ks++)
#pragma unroll
            for (int ai = 0; ai < 4; ai++)
#pragma unroll
                for (int bi = 0; bi < 2; bi++)
                    acc[A0 + ai][B0 + bi] = __builtin_amdgcn_mfma_f32_16x16x32_bf16(
                        af[ai][ks], bf[bi][ks], acc[A0 + ai][B0 + bi], 0, 0, 0);
        __builtin_amdgcn_s_setprio(0);
    };

    const int NT = K >> 6;

    STAGE_H(0, 0, 0); STAGE_H(0, 1, 0); STAGE_H(0, 2, 0); STAGE_H(0, 3, 0);
    asm volatile("s_waitcnt vmcnt(0)" ::: "memory");
    __builtin_amdgcn_s_barrier();

    bf16x8 aL[4][2], aH[4][2], bL[2][2], bH[2][2];

    for (int t = 0; t < NT; ++t) {
        const int sel = t & 1;
        const bool pf = (t + 1 < NT);
        // phase 0: (aL,bL)
        LDA4(aL, sel, 0); LDB2(bL, sel, 0);
        if (pf) STAGE_H(sel ^ 1, 0, t + 1);
        __builtin_amdgcn_s_barrier();
        MM(aL, bL, 0, 0);
        asm volatile("s_waitcnt vmcnt(4)" ::: "memory");
        __builtin_amdgcn_s_barrier();
        // phase 1: (aH,bL)
        LDA4(aH, sel, 1);
        if (pf) STAGE_H(sel ^ 1, 1, t + 1);
        __builtin_amdgcn_s_barrier();
        MM(aH, bL, 4, 0);
        asm volatile("s_waitcnt vmcnt(4)" ::: "memory");
        __builtin_amdgcn_s_barrier();
        // phase 2: (aH,bH)
        LDB2(bH, sel, 1);
        if (pf) STAGE_H(sel ^ 1, 2, t + 1);
        __builtin_amdgcn_s_barrier();
        MM(aH, bH, 4, 2);
        asm volatile("s_waitcnt vmcnt(4)" ::: "memory");
        __builtin_amdgcn_s_barrier();
        // phase 3: (aL,bH) — no new reads
        if (pf) STAGE_H(sel ^ 1, 3, t + 1);
        __builtin_amdgcn_s_barrier();
        MM(aL, bH, 0, 2);
        asm volatile("s_waitcnt vmcnt(4)" ::: "memory");
        __builtin_amdgcn_s_barrier();
    }
#undef STAGE_H

    // fused GLU epilogue: pairs (2bp, 2bp+1) -> out column j
#pragma unroll
    for (int bp = 0; bp < 2; bp++) {
        int j = (n0 >> 1) + wcn * 16 + 64 * bp + r16;
        float bsa = bias[j];
        float bsg = bias[j + 1024];
#pragma unroll
        for (int a_ = 0; a_ < 8; a_++) {
            int mr = m0 + wr * 16 + 32 * a_ + g4 * 4;
#pragma unroll
            for (int r = 0; r < 4; r++) {
                float av = acc[a_][2 * bp][r] + bsa;
                float gv = acc[a_][2 * bp + 1][r] + bsg;
                out[(size_t)(mr + r) * 1024 + j] = av * (1.f / (1.f + __expf(-gv)));
            }
        }
    }
}

// ---------------- flash attention v5: swapped-operand + deferred-PV pipeline ----------------
// iter u: QK(u) || PV(u-1) || softmax(u). K staged 1 tile ahead of V.
// Pl is per-wave private single buffer (PV reads P(u-1) before softmax writes P(u)).
__global__ __launch_bounds__(512, 4) void attn_kernel(const ushort* __restrict__ Q,
                                                      const ushort* __restrict__ Kt,
                                                      const ushort* __restrict__ Vt,
                                                      const int* __restrict__ mask,
                                                      ushort* __restrict__ xq) {
    __shared__ ushort Ks[2][8192];   // [64 kv][128 d], row=256B, XOR swz ((row&7)<<4 bytes)
    __shared__ ushort Vs[2][8192];   // [128 d][64 s],  row=128B, XOR swz ((d&7)<<4 bytes)
    __shared__ ushort Pl[8][1024];   // per-wave [16 q][64 kv], 128B rows, XOR swz ((q&7)<<4 bytes)

    const int tid = threadIdx.x;
    const int l = tid & 63, wid = tid >> 6;
    const int r16 = l & 15, g4 = l >> 4;
    const int id = blockIdx.x;
    const int bh = ((id >> 6) << 3) | (id & 7);   // same-bh blocks differ by 8 -> same XCD
    const int qb = (id >> 3) & 7;
    const int b = bh >> 3, h = bh & 7;
    const int q0 = qb * 128 + wid * 16;

    bf16x8 qf[4];
    const ushort* Qrow = Q + (size_t)(b * 1024 + q0 + r16) * 1024 + h * 128 + g4 * 8;
#pragma unroll
    for (int kf = 0; kf < 4; kf++) qf[kf] = *(const bf16x8*)(Qrow + kf * 32);

    const ushort* Kg = Kt + ((size_t)b * 1024) * 1024 + h * 128; // + s*1024 + d
    const ushort* Vg = Vt + (size_t)(b * 8 + h) * 128 * 1024;    // + d*1024 + s
    const int* mptr = mask + b * 1024;

    f32x4 xacc[8];
#pragma unroll
    for (int i = 0; i < 8; i++) xacc[i] = (f32x4){0.f, 0.f, 0.f, 0.f};
    float mrow = -INFINITY, lrow = 0.f, sclp = 0.f;

    char* Pme = (char*)&Pl[wid][0];
    const int pswz = (r16 & 7) << 4;

    auto STAGE_K = [&](int sel, int t) {
        const int kv0 = t * 64;
#pragma unroll
        for (int it = 0; it < 2; ++it) {
            int ob = it * 8192 + wid * 1024;
            int o = ob + l * 16;
            int row = o >> 8;
            int sc = (o & 255) ^ ((row & 7) << 4);
            const ushort* src = Kg + (size_t)(kv0 + row) * 1024 + (sc >> 1);
            __builtin_amdgcn_global_load_lds((const __attribute__((address_space(1))) void*)src,
                (__attribute__((address_space(3))) void*)((char*)&Ks[sel][0] + ob), 16, 0, 0);
        }
    };
    auto STAGE_V = [&](int sel, int t) {
        const int kv0 = t * 64;
#pragma unroll
        for (int it = 0; it < 2; ++it) {
            int ob = it * 8192 + wid * 1024;
            int o = ob + l * 16;
            int d = o >> 7;
            int sc = (o & 127) ^ ((d & 7) << 4);
            const ushort* src = Vg + (size_t)d * 1024 + kv0 + (sc >> 1);
            __builtin_amdgcn_global_load_lds((const __attribute__((address_space(1))) void*)src,
                (__attribute__((address_space(3))) void*)((char*)&Vs[sel][0] + ob), 16, 0, 0);
        }
    };

    // QK of tile u from Ks[sel] into s[], apply mask bits
    auto QK = [&](f32x4 (&s)[4], int sel, unsigned long long wt) {
        const char* Kb_ = (const char*)&Ks[sel][0];
#pragma unroll
        for (int cg = 0; cg < 4; cg++) {
            s[cg] = (f32x4){0.f, 0.f, 0.f, 0.f};
            const int rowk = cg * 16 + r16;
            const char* kr = Kb_ + rowk * 256;
            const int sw = (rowk & 7) << 4;
            __builtin_amdgcn_s_setprio(1);
#pragma unroll
            for (int kf = 0; kf < 4; kf++) {
                bf16x8 kfr = *(const bf16x8*)(kr + ((kf * 64 + g4 * 16) ^ sw));
                s[cg] = __builtin_amdgcn_mfma_f32_16x16x32_bf16(kfr, qf[kf], s[cg], 0, 0, 0);
            }
            __builtin_amdgcn_s_setprio(0);
            uint nib = (uint)(wt >> (cg * 16 + g4 * 4)) & 15u;
#pragma unroll
            for (int r = 0; r < 4; r++)
                if (!((nib >> r) & 1u)) s[cg][r] = -1e9f;
        }
    };
    // PV of the P currently in Pme, V from Vs[sel]; rescales xacc by sclp first
    auto PV = [&](int sel) {
        const char* Vb_ = (const char*)&Vs[sel][0];
        bf16x8 pfr[2];
#pragma unroll
        for (int ks = 0; ks < 2; ks++)
            pfr[ks] = *(const bf16x8*)(Pme + r16 * 128 + ((g4 * 16 + ks * 64) ^ pswz));
#pragma unroll
        for (int cg2 = 0; cg2 < 8; cg2++)
#pragma unroll
            for (int r = 0; r < 4; r++) xacc[cg2][r] *= sclp;
        __builtin_amdgcn_s_setprio(1);
#pragma unroll
        for (int ks = 0; ks < 2; ks++) {
#pragma unroll
            for (int cg2 = 0; cg2 < 8; cg2++) {
                const int d = cg2 * 16 + r16;
                bf16x8 vfr = *(const bf16x8*)(Vb_ + d * 128 + ((ks * 64 + g4 * 16) ^ ((d & 7) << 4)));
                xacc[cg2] = __builtin_amdgcn_mfma_f32_16x16x32_bf16(vfr, pfr[ks], xacc[cg2], 0, 0, 0);
            }
        }
        __builtin_amdgcn_s_setprio(0);
    };
    // softmax on s[]: updates mrow, lrow, sclp; writes P to Pme
    auto SOFTMAX = [&](f32x4 (&s)[4]) {
        float pmax = -INFINITY;
#pragma unroll
        for (int cg = 0; cg < 4; cg++)
#pragma unroll
            for (int r = 0; r < 4; r++) pmax = fmaxf(pmax, s[cg][r]);
        pmax = fmaxf(pmax, __shfl_xor(pmax, 16));
        pmax = fmaxf(pmax, __shfl_xor(pmax, 32));
        float mn = fmaxf(mrow, pmax);
        sclp = __expf(mrow - mn);
        mrow = mn;
        float rsum = 0.f;
#pragma unroll
        for (int cg = 0; cg < 4; cg++)
#pragma unroll
            for (int r = 0; r < 4; r++) {
                float p = __expf(s[cg][r] - mn);
                s[cg][r] = p;
                rsum += p;
            }
        rsum += __shfl_xor(rsum, 16);
        rsum += __shfl_xor(rsum, 32);
        lrow = lrow * sclp + rsum;
#pragma unroll
        for (int cg = 0; cg < 4; cg++) {
            uint lo = ((uint)f2b(s[cg][1]) << 16) | f2b(s[cg][0]);
            uint hi = ((uint)f2b(s[cg][3]) << 16) | f2b(s[cg][2]);
            uint2 pk; pk.x = lo; pk.y = hi;
            *(uint2*)(Pme + r16 * 128 + ((cg * 32 + g4 * 8) ^ pswz)) = pk;
        }
    };

    // ---- prologue: tile 0 ----
    STAGE_K(0, 0);
    int mv = mptr[l];
    asm volatile("s_waitcnt vmcnt(0)" ::: "memory");
    __syncthreads();
    STAGE_K(1, 1);
    STAGE_V(0, 0);
    unsigned long long wt = __ballot(mv != 0);
    mv = mptr[64 + l];
    {
        f32x4 s0[4];
        QK(s0, 0, wt);
        SOFTMAX(s0);   // sclp = exp(-inf - mn) = 0; xacc is zero anyway
    }
    int kc = 1, vc = 0;

    // ---- main loop: QK(u) || PV(u-1) || softmax(u) ----
    for (int u = 1; u < 16; ++u) {
        wt = __ballot(mv != 0);
        asm volatile("s_waitcnt vmcnt(0)" ::: "memory");
        __syncthreads();
        if (u < 15) STAGE_K(kc ^ 1, u + 1);
        STAGE_V(vc ^ 1, u);
        if (u < 15) mv = mptr[(u + 1) * 64 + l];

        f32x4 sn[4];
        QK(sn, kc, wt);     // tile u
        PV(vc);             // tile u-1 (reads Pme before SOFTMAX overwrites it)
        SOFTMAX(sn);        // tile u -> writes P(u) into Pme

        kc ^= 1; vc ^= 1;
    }

    // ---- epilogue: PV(15) ----
    asm volatile("s_waitcnt vmcnt(0)" ::: "memory");
    __syncthreads();
    PV(vc);

    const float inv = 1.f / lrow;
    const size_t orow = (size_t)(b * 1024 + q0 + r16) * 2048 + h * 128;
#pragma unroll
    for (int cg2 = 0; cg2 < 8; cg2++) {
#pragma unroll
        for (int r = 0; r < 4; r++) {
            xq[orow + cg2 * 16 + g4 * 4 + r] = f2b(xacc[cg2][r] * inv);
        }
    }
}

extern "C" void kernel_launch(void* const* d_in, const int* in_sizes, int n_in,
                              void* d_out, int out_size, void* d_ws, size_t ws_size,
                              hipStream_t stream) {
    const float* query = (const float*)d_in[0];
    const float* value = (const float*)d_in[1];
    const float* key   = (const float*)d_in[2];
    const int*   mask  = (const int*)d_in[3];
    const float* ln_a  = (const float*)d_in[4];
    const float* ln_b  = (const float*)d_in[5];
    const float* wq    = (const float*)d_in[6];
    const float* bq    = (const float*)d_in[7];
    const float* wk    = (const float*)d_in[8];
    const float* bk    = (const float*)d_in[9];
    const float* wv    = (const float*)d_in[10];
    const float* bv    = (const float*)d_in[11];
    const float* waoa  = (const float*)d_in[12];
    const float* baoa  = (const float*)d_in[13];
    float* out = (float*)d_out;

    char* w8 = (char*)d_ws;
    ushort* xq   = (ushort*)(w8);                 // 8192x2048 bf16 ([x | q_ln])
    ushort* Qb   = (ushort*)(w8 + 33554432);      // 8192x1024 bf16
    ushort* Kb   = (ushort*)(w8 + 50331648);      // 8192x1024 bf16
    ushort* Vt   = (ushort*)(w8 + 67108864);      // (B,H,128,S) bf16
    ushort* keyb = (ushort*)(w8 + 83886080);      // 8192x1024 bf16
    ushort* valb = (ushort*)(w8 + 100663296);     // 8192x1024 bf16
    ushort* wqb  = (ushort*)(w8 + 117440512);
    ushort* wkb  = (ushort*)(w8 + 119537664);
    ushort* wvb  = (ushort*)(w8 + 121634816);
    ushort* wab  = (ushort*)(w8 + 123731968);     // 2048x2048 bf16 (PERMUTED)

    cast_kernel<<<8192, 256, 0, stream>>>(key, keyb);
    cast_kernel<<<8192, 256, 0, stream>>>(value, valb);
    cast_kernel<<<1024, 256, 0, stream>>>(wq, wqb);
    cast_kernel<<<1024, 256, 0, stream>>>(wk, wkb);
    cast_kernel<<<1024, 256, 0, stream>>>(wv, wvb);
    cast_permute_aoa<<<4096, 256, 0, stream>>>(waoa, wab);
    ln_kernel<<<8192, 256, 0, stream>>>(query, ln_a, ln_b, xq);

    const float qscale = 0.08838834764831845f; // 1/sqrt(128)
    gemm2<<<512, 256, 0, stream>>>(xq + 1024, 2048, wqb, 1024, bq, Qb, 1024, 1024, 8, qscale, 0);
    gemm2<<<512, 256, 0, stream>>>(keyb, 1024, wkb, 1024, bk, Kb, 1024, 1024, 8, 1.f, 0);
    gemm2<<<512, 256, 0, stream>>>(valb, 1024, wvb, 1024, bv, Vt, 0, 1024, 8, 1.f, 1);

    attn_kernel<<<512, 512, 0, stream>>>(Qb, Kb, Vt, mask, xq);

    // AOA + GLU fused: M=8192, N=2048 (permuted), K=2048 -> 256 blocks
    gemm3<<<256, 512, 0, stream>>>(xq, 2048, wab, 2048, baoa, out, 2048, 8);
}

// Round 7
// 241.405 us; speedup vs baseline: 2.7120x; 1.0049x over previous
//
#include <hip/hip_runtime.h>

typedef __attribute__((ext_vector_type(8))) __bf16 bf16x8;
typedef __attribute__((ext_vector_type(4))) float f32x4;

__device__ __forceinline__ ushort f2b(float f) {
    uint u = __builtin_bit_cast(uint, f);
    u += 0x7fffu + ((u >> 16) & 1u);
    return (ushort)(u >> 16);
}
__device__ __forceinline__ float b2f(ushort h) {
    uint u = ((uint)h) << 16;
    return __builtin_bit_cast(float, u);
}

// ---------------- cast f32 -> bf16 (vec4) ----------------
__global__ __launch_bounds__(256) void cast_kernel(const float* __restrict__ src,
                                                   ushort* __restrict__ dst) {
    size_t i = ((size_t)blockIdx.x * 256 + threadIdx.x) * 4;
    float4 v = *(const float4*)(src + i);
    ushort4 o;
    o.x = f2b(v.x); o.y = f2b(v.y); o.z = f2b(v.z); o.w = f2b(v.w);
    *(ushort4*)(dst + i) = o;
}

// ---------------- cast + ROW-PERMUTE w_aoa so (a_j, g_j) output columns pair up ----------------
// dst row n' = src row q(n') = ((n'&63) | ((n'>>7)<<6)) + 1024*((n'>>6)&1)
__global__ __launch_bounds__(256) void cast_permute_aoa(const float* __restrict__ src,
                                                        ushort* __restrict__ dst) {
    int n1 = blockIdx.x >> 1;
    int c = (blockIdx.x & 1) * 1024 + threadIdx.x * 4;
    int q = ((n1 & 63) | ((n1 >> 7) << 6)) + ((n1 >> 6) & 1) * 1024;
    float4 v = *(const float4*)(src + (size_t)q * 2048 + c);
    ushort4 o;
    o.x = f2b(v.x); o.y = f2b(v.y); o.z = f2b(v.z); o.w = f2b(v.w);
    *(ushort4*)(dst + (size_t)n1 * 2048 + c) = o;
}

// ---------------- LayerNorm(query) -> bf16 into xq[:,1024:2048] ----------------
__global__ __launch_bounds__(256) void ln_kernel(const float* __restrict__ x,
                                                 const float* __restrict__ ga,
                                                 const float* __restrict__ be,
                                                 ushort* __restrict__ xq) {
    const int row = blockIdx.x, tid = threadIdx.x;
    __shared__ float red[4];
    float4 v = ((const float4*)(x + (size_t)row * 1024))[tid];
    float sm = v.x + v.y + v.z + v.w;
    for (int off = 32; off; off >>= 1) sm += __shfl_xor(sm, off);
    if ((tid & 63) == 0) red[tid >> 6] = sm;
    __syncthreads();
    float mean = (red[0] + red[1] + red[2] + red[3]) * (1.f / 1024.f);
    __syncthreads();
    float dx = v.x - mean, dy = v.y - mean, dz = v.z - mean, dw = v.w - mean;
    float s2 = dx * dx + dy * dy + dz * dz + dw * dw;
    for (int off = 32; off; off >>= 1) s2 += __shfl_xor(s2, off);
    if ((tid & 63) == 0) red[tid >> 6] = s2;
    __syncthreads();
    float var = (red[0] + red[1] + red[2] + red[3]) * (1.f / 1023.f);
    float inv = 1.f / (sqrtf(var) + 1e-6f);
    float4 g = ((const float4*)ga)[tid];
    float4 bb = ((const float4*)be)[tid];
    ushort4 o;
    o.x = f2b(g.x * dx * inv + bb.x);
    o.y = f2b(g.y * dy * inv + bb.y);
    o.z = f2b(g.z * dz * inv + bb.z);
    o.w = f2b(g.w * dw * inv + bb.w);
    *(ushort4*)&xq[(size_t)row * 2048 + 1024 + tid * 4] = o;
}

// ---------------- GEMM v4: 256x256, BK=64, full-tile prefetch + 2 counted gates/tile ----------------
// MODE 0: fused QKV. N=3072 over regions {Q,K,V}; A selected per region; outputs
//   Qb/Kb row-major bf16 (Q scaled by qscale) and Vt transposed (B,H,128,S).
// MODE 1: AOA + fused GLU. B = permuted w_aoa; out f32 (M x 1024) = a*sigmoid(g).
// Schedule per K-tile t (sel=t&1): ph0 {rd aL,bL | STAGE8(t+1) order AL,BL,AH,BH |
// bar | MM | vmcnt(8) bar} ph1 {rd aH | bar | MM | bar} ph2 {rd bH | bar | MM | bar}
// ph3 {MM | vmcnt(4) bar}. vmcnt(8) retires AH,BH(t) (issued @ t-1.ph0, 4 phases
// slack); vmcnt(4) retires AL,BL(t+1). Last tile peeled with vmcnt(0).
template <int MODE>
__global__ __launch_bounds__(512, 2) void gemm4(const ushort* __restrict__ Aq, int ldaq,
                                                const ushort* __restrict__ Ak,
                                                const ushort* __restrict__ Av,
                                                const ushort* __restrict__ B, int ldb,
                                                const float* __restrict__ bias0,
                                                const float* __restrict__ bias1,
                                                const float* __restrict__ bias2,
                                                void* __restrict__ out0,
                                                void* __restrict__ out1,
                                                void* __restrict__ out2,
                                                int K, int NB, float qscale) {
    __shared__ ushort lds[2][32768];   // per buf: A 256x64 (32KB) | B 256x64 (32KB)

    const int tid = threadIdx.x;
    const int w = tid >> 6, l = tid & 63;
    const int wr = w >> 2, wcn = w & 3;
    const int r16 = l & 15, g4 = l >> 4;

    const int bid = blockIdx.x;
    const int cpx = gridDim.x >> 3;
    const int swz = (bid & 7) * cpx + (bid >> 3);
    const int m0 = (swz / NB) * 256;
    const int n0 = (swz % NB) * 256;

    // region select (wave-uniform). MODE1: region 0 semantics with A=Aq.
    const int region = (MODE == 0) ? (n0 >> 10) : 0;
    const ushort* A = (MODE == 0) ? (region == 0 ? Aq : (region == 1 ? Ak : Av)) : Aq;
    const int lda = (MODE == 0) ? (region == 0 ? ldaq : 1024) : ldaq;

    const int srow8 = l >> 3;
    const int sxor8 = ((l & 7) ^ srow8) * 8;
    const ushort* As0 = A + (size_t)(m0 + w * 8 + srow8) * lda + sxor8;
    const ushort* Bs0 = B + (size_t)(n0 + w * 8 + srow8) * ldb + sxor8;

    f32x4 acc[8][4];
#pragma unroll
    for (int i = 0; i < 8; i++)
#pragma unroll
        for (int j = 0; j < 4; j++) acc[i][j] = (f32x4){0.f, 0.f, 0.f, 0.f};

    const int sw16 = (r16 & 7) << 4;
    char* ldsb = (char*)&lds[0][0];

#define GL16(src_, dst_)                                                        \
    __builtin_amdgcn_global_load_lds(                                           \
        (const __attribute__((address_space(1))) void*)(src_),                  \
        (__attribute__((address_space(3))) void*)(dst_), 16, 0, 0)

    // issue order matters for vmcnt accounting: AL(2), BL(2), AH(2), BH(2)
    auto STAGE8 = [&](int sel, int kt) {
        const size_t ko = (size_t)kt * 64;
#pragma unroll
        for (int li = 0; li < 2; li++)   // AL
            GL16(As0 + (size_t)(li * 64) * lda + ko,
                 ldsb + sel * 65536 + li * 8192 + w * 1024);
#pragma unroll
        for (int li = 0; li < 2; li++)   // BL
            GL16(Bs0 + (size_t)(li * 64) * ldb + ko,
                 ldsb + sel * 65536 + 32768 + li * 8192 + w * 1024);
#pragma unroll
        for (int li = 0; li < 2; li++)   // AH
            GL16(As0 + (size_t)(128 + li * 64) * lda + ko,
                 ldsb + sel * 65536 + 16384 + li * 8192 + w * 1024);
#pragma unroll
        for (int li = 0; li < 2; li++)   // BH
            GL16(Bs0 + (size_t)(128 + li * 64) * ldb + ko,
                 ldsb + sel * 65536 + 32768 + 16384 + li * 8192 + w * 1024);
    };

    auto LDA4 = [&](bf16x8 (&dst)[4][2], int sel, int half) {
#pragma unroll
        for (int ai = 0; ai < 4; ai++)
#pragma unroll
            for (int ks = 0; ks < 2; ks++)
                dst[ai][ks] = *(const bf16x8*)(ldsb + sel * 65536 + half * 16384 +
                                               (wr * 16 + 32 * ai + r16) * 128 +
                                               ((ks * 64 + g4 * 16) ^ sw16));
    };
    auto LDB2 = [&](bf16x8 (&dst)[2][2], int sel, int half) {
#pragma unroll
        for (int bi = 0; bi < 2; bi++)
#pragma unroll
            for (int ks = 0; ks < 2; ks++)
                dst[bi][ks] = *(const bf16x8*)(ldsb + sel * 65536 + 32768 + half * 16384 +
                                               (wcn * 16 + 64 * bi + r16) * 128 +
                                               ((ks * 64 + g4 * 16) ^ sw16));
    };
    auto MM = [&](bf16x8 (&af)[4][2], bf16x8 (&bf)[2][2], int A0, int B0) {
        __builtin_amdgcn_s_setprio(1);
#pragma unroll
        for (int ks = 0; ks < 2; ks++)
#pragma unroll
            for (int ai = 0; ai < 4; ai++)
#pragma unroll
                for (int bi = 0; bi < 2; bi++)
                    acc[A0 + ai][B0 + bi] = __builtin_amdgcn_mfma_f32_16x16x32_bf16(
                        af[ai][ks], bf[bi][ks], acc[A0 + ai][B0 + bi], 0, 0, 0);
        __builtin_amdgcn_s_setprio(0);
    };

    const int NT = K >> 6;

    STAGE8(0, 0);
    asm volatile("s_waitcnt vmcnt(0)" ::: "memory");
    __builtin_amdgcn_s_barrier();

    bf16x8 aL[4][2], aH[4][2], bL[2][2], bH[2][2];

    for (int t = 0; t < NT - 1; ++t) {
        const int sel = t & 1;
        // ph0: (aL,bL) + full-tile prefetch
        LDA4(aL, sel, 0); LDB2(bL, sel, 0);
        STAGE8(sel ^ 1, t + 1);
        __builtin_amdgcn_s_barrier();
        MM(aL, bL, 0, 0);
        asm volatile("s_waitcnt vmcnt(8)" ::: "memory");   // AH,BH(t) landed
        __builtin_amdgcn_s_barrier();
        // ph1: (aH,bL)
        LDA4(aH, sel, 1);
        __builtin_amdgcn_s_barrier();
        MM(aH, bL, 4, 0);
        __builtin_amdgcn_s_barrier();
        // ph2: (aH,bH)
        LDB2(bH, sel, 1);
        __builtin_amdgcn_s_barrier();
        MM(aH, bH, 4, 2);
        __builtin_amdgcn_s_barrier();
        // ph3: (aL,bH)
        MM(aL, bH, 0, 2);
        asm volatile("s_waitcnt vmcnt(4)" ::: "memory");   // AL,BL(t+1) landed
        __builtin_amdgcn_s_barrier();
    }
    {   // peeled last tile (no prefetch)
        const int sel = (NT - 1) & 1;
        LDA4(aL, sel, 0); LDB2(bL, sel, 0);
        __builtin_amdgcn_s_barrier();
        MM(aL, bL, 0, 0);
        asm volatile("s_waitcnt vmcnt(0)" ::: "memory");   // AH,BH landed
        __builtin_amdgcn_s_barrier();
        LDA4(aH, sel, 1);
        LDB2(bH, sel, 1);
        MM(aH, bL, 4, 0);
        MM(aH, bH, 4, 2);
        MM(aL, bH, 0, 2);
    }
#undef GL16

    if (MODE == 1) {
        // fused GLU epilogue: pairs (2bp, 2bp+1) -> out column j
        float* out = (float*)out0;
#pragma unroll
        for (int bp = 0; bp < 2; bp++) {
            int j = (n0 >> 1) + wcn * 16 + 64 * bp + r16;
            float bsa = bias0[j];
            float bsg = bias0[j + 1024];
#pragma unroll
            for (int a_ = 0; a_ < 8; a_++) {
                int mr = m0 + wr * 16 + 32 * a_ + g4 * 4;
#pragma unroll
                for (int r = 0; r < 4; r++) {
                    float av = acc[a_][2 * bp][r] + bsa;
                    float gv = acc[a_][2 * bp + 1][r] + bsg;
                    out[(size_t)(mr + r) * 1024 + j] = av * (1.f / (1.f + __expf(-gv)));
                }
            }
        }
    } else {
        const int nr0 = n0 & 1023;
        const float* bias = region == 0 ? bias0 : (region == 1 ? bias1 : bias2);
        const float scale = region == 0 ? qscale : 1.f;
        if (region < 2) {
            ushort* C = (ushort*)(region == 0 ? out0 : out1);
#pragma unroll
            for (int b_ = 0; b_ < 4; b_++) {
                int n = nr0 + wcn * 16 + 64 * b_ + r16;
                float bs = bias[n];
#pragma unroll
                for (int a_ = 0; a_ < 8; a_++) {
                    int mr = m0 + wr * 16 + 32 * a_ + g4 * 4;
#pragma unroll
                    for (int r = 0; r < 4; r++)
                        C[(size_t)(mr + r) * 1024 + n] = f2b((acc[a_][b_][r] + bs) * scale);
                }
            }
        } else {
            // V region: Vt[(b*8+h)*128 + d][s]
            ushort* Vt = (ushort*)out2;
#pragma unroll
            for (int b_ = 0; b_ < 4; b_++) {
                int n = nr0 + wcn * 16 + 64 * b_ + r16;
                float bs = bias[n];
                int h = n >> 7, d = n & 127;
#pragma unroll
                for (int a_ = 0; a_ < 8; a_++) {
                    int mr = m0 + wr * 16 + 32 * a_ + g4 * 4;
                    int bb = mr >> 10, s_ = mr & 1023;
                    ushort4 o;
                    o.x = f2b(acc[a_][b_][0] + bs);
                    o.y = f2b(acc[a_][b_][1] + bs);
                    o.z = f2b(acc[a_][b_][2] + bs);
                    o.w = f2b(acc[a_][b_][3] + bs);
                    *(ushort4*)&Vt[((size_t)(bb * 8 + h) * 128 + d) * 1024 + s_] = o;
                }
            }
        }
    }
}

// ---------------- flash attention v5: swapped-operand + deferred-PV pipeline ----------------
__global__ __launch_bounds__(512, 4) void attn_kernel(const ushort* __restrict__ Q,
                                                      const ushort* __restrict__ Kt,
                                                      const ushort* __restrict__ Vt,
                                                      const int* __restrict__ mask,
                                                      ushort* __restrict__ xq) {
    __shared__ ushort Ks[2][8192];   // [64 kv][128 d], row=256B, XOR swz ((row&7)<<4 bytes)
    __shared__ ushort Vs[2][8192];   // [128 d][64 s],  row=128B, XOR swz ((d&7)<<4 bytes)
    __shared__ ushort Pl[8][1024];   // per-wave [16 q][64 kv], 128B rows, XOR swz ((q&7)<<4 bytes)

    const int tid = threadIdx.x;
    const int l = tid & 63, wid = tid >> 6;
    const int r16 = l & 15, g4 = l >> 4;
    const int id = blockIdx.x;
    const int bh = ((id >> 6) << 3) | (id & 7);
    const int qb = (id >> 3) & 7;
    const int b = bh >> 3, h = bh & 7;
    const int q0 = qb * 128 + wid * 16;

    bf16x8 qf[4];
    const ushort* Qrow = Q + (size_t)(b * 1024 + q0 + r16) * 1024 + h * 128 + g4 * 8;
#pragma unroll
    for (int kf = 0; kf < 4; kf++) qf[kf] = *(const bf16x8*)(Qrow + kf * 32);

    const ushort* Kg = Kt + ((size_t)b * 1024) * 1024 + h * 128;
    const ushort* Vg = Vt + (size_t)(b * 8 + h) * 128 * 1024;
    const int* mptr = mask + b * 1024;

    f32x4 xacc[8];
#pragma unroll
    for (int i = 0; i < 8; i++) xacc[i] = (f32x4){0.f, 0.f, 0.f, 0.f};
    float mrow = -INFINITY, lrow = 0.f, sclp = 0.f;

    char* Pme = (char*)&Pl[wid][0];
    const int pswz = (r16 & 7) << 4;

    auto STAGE_K = [&](int sel, int t) {
        const int kv0 = t * 64;
#pragma unroll
        for (int it = 0; it < 2; ++it) {
            int ob = it * 8192 + wid * 1024;
            int o = ob + l * 16;
            int row = o >> 8;
            int sc = (o & 255) ^ ((row & 7) << 4);
            const ushort* src = Kg + (size_t)(kv0 + row) * 1024 + (sc >> 1);
            __builtin_amdgcn_global_load_lds((const __attribute__((address_space(1))) void*)src,
                (__attribute__((address_space(3))) void*)((char*)&Ks[sel][0] + ob), 16, 0, 0);
        }
    };
    auto STAGE_V = [&](int sel, int t) {
        const int kv0 = t * 64;
#pragma unroll
        for (int it = 0; it < 2; ++it) {
            int ob = it * 8192 + wid * 1024;
            int o = ob + l * 16;
            int d = o >> 7;
            int sc = (o & 127) ^ ((d & 7) << 4);
            const ushort* src = Vg + (size_t)d * 1024 + kv0 + (sc >> 1);
            __builtin_amdgcn_global_load_lds((const __attribute__((address_space(1))) void*)src,
                (__attribute__((address_space(3))) void*)((char*)&Vs[sel][0] + ob), 16, 0, 0);
        }
    };

    auto QK = [&](f32x4 (&s)[4], int sel, unsigned long long wt) {
        const char* Kb_ = (const char*)&Ks[sel][0];
#pragma unroll
        for (int cg = 0; cg < 4; cg++) {
            s[cg] = (f32x4){0.f, 0.f, 0.f, 0.f};
            const int rowk = cg * 16 + r16;
            const char* kr = Kb_ + rowk * 256;
            const int sw = (rowk & 7) << 4;
            __builtin_amdgcn_s_setprio(1);
#pragma unroll
            for (int kf = 0; kf < 4; kf++) {
                bf16x8 kfr = *(const bf16x8*)(kr + ((kf * 64 + g4 * 16) ^ sw));
                s[cg] = __builtin_amdgcn_mfma_f32_16x16x32_bf16(kfr, qf[kf], s[cg], 0, 0, 0);
            }
            __builtin_amdgcn_s_setprio(0);
            uint nib = (uint)(wt >> (cg * 16 + g4 * 4)) & 15u;
#pragma unroll
            for (int r = 0; r < 4; r++)
                if (!((nib >> r) & 1u)) s[cg][r] = -1e9f;
        }
    };
    auto PV = [&](int sel) {
        const char* Vb_ = (const char*)&Vs[sel][0];
        bf16x8 pfr[2];
#pragma unroll
        for (int ks = 0; ks < 2; ks++)
            pfr[ks] = *(const bf16x8*)(Pme + r16 * 128 + ((g4 * 16 + ks * 64) ^ pswz));
#pragma unroll
        for (int cg2 = 0; cg2 < 8; cg2++)
#pragma unroll
            for (int r = 0; r < 4; r++) xacc[cg2][r] *= sclp;
        __builtin_amdgcn_s_setprio(1);
#pragma unroll
        for (int ks = 0; ks < 2; ks++) {
#pragma unroll
            for (int cg2 = 0; cg2 < 8; cg2++) {
                const int d = cg2 * 16 + r16;
                bf16x8 vfr = *(const bf16x8*)(Vb_ + d * 128 + ((ks * 64 + g4 * 16) ^ ((d & 7) << 4)));
                xacc[cg2] = __builtin_amdgcn_mfma_f32_16x16x32_bf16(vfr, pfr[ks], xacc[cg2], 0, 0, 0);
            }
        }
        __builtin_amdgcn_s_setprio(0);
    };
    auto SOFTMAX = [&](f32x4 (&s)[4]) {
        float pmax = -INFINITY;
#pragma unroll
        for (int cg = 0; cg < 4; cg++)
#pragma unroll
            for (int r = 0; r < 4; r++) pmax = fmaxf(pmax, s[cg][r]);
        pmax = fmaxf(pmax, __shfl_xor(pmax, 16));
        pmax = fmaxf(pmax, __shfl_xor(pmax, 32));
        float mn = fmaxf(mrow, pmax);
        sclp = __expf(mrow - mn);
        mrow = mn;
        float rsum = 0.f;
#pragma unroll
        for (int cg = 0; cg < 4; cg++)
#pragma unroll
            for (int r = 0; r < 4; r++) {
                float p = __expf(s[cg][r] - mn);
                s[cg][r] = p;
                rsum += p;
            }
        rsum += __shfl_xor(rsum, 16);
        rsum += __shfl_xor(rsum, 32);
        lrow = lrow * sclp + rsum;
#pragma unroll
        for (int cg = 0; cg < 4; cg++) {
            uint lo = ((uint)f2b(s[cg][1]) << 16) | f2b(s[cg][0]);
            uint hi = ((uint)f2b(s[cg][3]) << 16) | f2b(s[cg][2]);
            uint2 pk; pk.x = lo; pk.y = hi;
            *(uint2*)(Pme + r16 * 128 + ((cg * 32 + g4 * 8) ^ pswz)) = pk;
        }
    };

    STAGE_K(0, 0);
    int mv = mptr[l];
    asm volatile("s_waitcnt vmcnt(0)" ::: "memory");
    __syncthreads();
    STAGE_K(1, 1);
    STAGE_V(0, 0);
    unsigned long long wt = __ballot(mv != 0);
    mv = mptr[64 + l];
    {
        f32x4 s0[4];
        QK(s0, 0, wt);
        SOFTMAX(s0);
    }
    int kc = 1, vc = 0;

    for (int u = 1; u < 16; ++u) {
        wt = __ballot(mv != 0);
        asm volatile("s_waitcnt vmcnt(0)" ::: "memory");
        __syncthreads();
        if (u < 15) STAGE_K(kc ^ 1, u + 1);
        STAGE_V(vc ^ 1, u);
        if (u < 15) mv = mptr[(u + 1) * 64 + l];

        f32x4 sn[4];
        QK(sn, kc, wt);
        PV(vc);
        SOFTMAX(sn);

        kc ^= 1; vc ^= 1;
    }

    asm volatile("s_waitcnt vmcnt(0)" ::: "memory");
    __syncthreads();
    PV(vc);

    const float inv = 1.f / lrow;
    const size_t orow = (size_t)(b * 1024 + q0 + r16) * 2048 + h * 128;
#pragma unroll
    for (int cg2 = 0; cg2 < 8; cg2++) {
#pragma unroll
        for (int r = 0; r < 4; r++) {
            xq[orow + cg2 * 16 + g4 * 4 + r] = f2b(xacc[cg2][r] * inv);
        }
    }
}

extern "C" void kernel_launch(void* const* d_in, const int* in_sizes, int n_in,
                              void* d_out, int out_size, void* d_ws, size_t ws_size,
                              hipStream_t stream) {
    const float* query = (const float*)d_in[0];
    const float* value = (const float*)d_in[1];
    const float* key   = (const float*)d_in[2];
    const int*   mask  = (const int*)d_in[3];
    const float* ln_a  = (const float*)d_in[4];
    const float* ln_b  = (const float*)d_in[5];
    const float* wq    = (const float*)d_in[6];
    const float* bq    = (const float*)d_in[7];
    const float* wk    = (const float*)d_in[8];
    const float* bk    = (const float*)d_in[9];
    const float* wv    = (const float*)d_in[10];
    const float* bv    = (const float*)d_in[11];
    const float* waoa  = (const float*)d_in[12];
    const float* baoa  = (const float*)d_in[13];
    float* out = (float*)d_out;

    char* w8 = (char*)d_ws;
    ushort* xq   = (ushort*)(w8);                 // 8192x2048 bf16 ([x | q_ln])
    ushort* Qb   = (ushort*)(w8 + 33554432);      // 8192x1024 bf16
    ushort* Kb   = (ushort*)(w8 + 50331648);      // 8192x1024 bf16
    ushort* Vt   = (ushort*)(w8 + 67108864);      // (B,H,128,S) bf16
    ushort* keyb = (ushort*)(w8 + 83886080);      // 8192x1024 bf16
    ushort* valb = (ushort*)(w8 + 100663296);     // 8192x1024 bf16
    ushort* wqb  = (ushort*)(w8 + 117440512);     // 3x 1024x1024 bf16, CONTIGUOUS (wq|wk|wv)
    ushort* wkb  = (ushort*)(w8 + 119537664);
    ushort* wvb  = (ushort*)(w8 + 121634816);
    ushort* wab  = (ushort*)(w8 + 123731968);     // 2048x2048 bf16 (PERMUTED)

    cast_kernel<<<8192, 256, 0, stream>>>(key, keyb);
    cast_kernel<<<8192, 256, 0, stream>>>(value, valb);
    cast_kernel<<<1024, 256, 0, stream>>>(wq, wqb);
    cast_kernel<<<1024, 256, 0, stream>>>(wk, wkb);
    cast_kernel<<<1024, 256, 0, stream>>>(wv, wvb);
    cast_permute_aoa<<<4096, 256, 0, stream>>>(waoa, wab);
    ln_kernel<<<8192, 256, 0, stream>>>(query, ln_a, ln_b, xq);

    const float qscale = 0.08838834764831845f; // 1/sqrt(128)

    // fused QKV: M=8192, N=3072 (Q|K|V regions), K=1024 -> 32x12 = 384 blocks
    gemm4<0><<<384, 512, 0, stream>>>(xq + 1024, 2048, keyb, valb,
                                      wqb, 1024, bq, bk, bv,
                                      Qb, Kb, Vt, 1024, 12, qscale);

    attn_kernel<<<512, 512, 0, stream>>>(Qb, Kb, Vt, mask, xq);

    // AOA + GLU fused: M=8192, N=2048 (permuted), K=2048 -> 256 blocks
    gemm4<1><<<256, 512, 0, stream>>>(xq, 2048, nullptr, nullptr,
                                      wab, 2048, baoa, nullptr, nullptr,
                                      out, nullptr, nullptr, 2048, 8, 1.f);
}